// Round 8
// baseline (458.210 us; speedup 1.0000x reference)
//
#include <hip/hip_runtime.h>
#include <hip/hip_bf16.h>
#include <cstdint>
#include <math.h>

typedef unsigned short u16;
typedef unsigned int u32;
typedef __bf16 bh;
typedef bh bh8 __attribute__((ext_vector_type(8)));
typedef float f32x4 __attribute__((ext_vector_type(4)));

#define SCALE_F 0.04419417382415922f  // 512^-0.5

__device__ __forceinline__ float bf2f(u16 u) {
    union { float f; unsigned int i; } v; v.i = ((unsigned int)u) << 16; return v.f;
}
__device__ __forceinline__ u16 f2bf(float f) {
    __hip_bfloat16 h = __float2bfloat16(f);
    return __builtin_bit_cast(u16, h);
}
__device__ __forceinline__ bh8 ld8_f32(const float* p) {
    float4 f0 = *(const float4*)p;
    float4 f1 = *(const float4*)(p + 4);
    bh8 r;
    r[0] = (bh)f0.x; r[1] = (bh)f0.y; r[2] = (bh)f0.z; r[3] = (bh)f0.w;
    r[4] = (bh)f1.x; r[5] = (bh)f1.y; r[6] = (bh)f1.z; r[7] = (bh)f1.w;
    return r;
}

// ordered-uint transforms (monotone with float order)
__device__ __forceinline__ u32 ordf(float f) {
    u32 u = __float_as_uint(f);
    return u ^ ((u32)((int)u >> 31) | 0x80000000u);
}
__device__ __forceinline__ float unordf(u32 s) {
    u32 u = (s & 0x80000000u) ? (s ^ 0x80000000u) : ~s;
    return __uint_as_float(u);
}
// 24-bit ordered value | 8-bit inverted local col idx (tie -> smaller idx wins)
__device__ __forceinline__ u32 pack_vi(float v, int inv_idx) {
    return (ordf(v) & 0xFFFFFF00u) | (u32)inv_idx;
}
__device__ __forceinline__ float unpack_v(u32 p) {
    return unordf(p & 0xFFFFFF00u);
}

// direct global->LDS 16B per lane; lds base wave-uniform (dest = base + lane*16)
__device__ __forceinline__ void gl_lds16(const u16* g, u16* l) {
    __builtin_amdgcn_global_load_lds(
        (const __attribute__((address_space(1))) void*)g,
        (__attribute__((address_space(3))) void*)l, 16, 0, 0);
}

// ---------------------------------------------------------------------------
// 6 weight transposes (fp32 [R,C] -> bf16 [C,R]) + x fp32->bf16, one dispatch
__global__ void transpose_cvt(const float* s0, u16* d0, const float* s1, u16* d1,
                              const float* s2, u16* d2, const float* s3, u16* d3,
                              const float* s4, u16* d4, const float* s5, u16* d5,
                              const float* xs, u16* xd) {
    int b = blockIdx.x;
    if (b >= 1664) {  // cvt_x part: 4096 blocks, 8 elems/thread
        int t = threadIdx.y * 32 + threadIdx.x;
        size_t i = ((size_t)(b - 1664) * 256 + t) * 8;
        *(bh8*)(xd + i) = ld8_f32(xs + i);
        return;
    }
    __shared__ float tsh[32][33];
    const float* src; u16* dst; int R, C, tt;
    if      (b < 512)  { src = s0; dst = d0; R = 1024; C = 512; tt = b; }
    else if (b < 768)  { src = s1; dst = d1; R = 512;  C = 512; tt = b - 512; }
    else if (b < 1024) { src = s2; dst = d2; R = 512;  C = 512; tt = b - 768; }
    else if (b < 1280) { src = s3; dst = d3; R = 512;  C = 512; tt = b - 1024; }
    else if (b < 1536) { src = s4; dst = d4; R = 512;  C = 512; tt = b - 1280; }
    else               { src = s5; dst = d5; R = 512;  C = 256; tt = b - 1536; }
    int ntx = C >> 5;
    int bx = (tt % ntx) * 32, by = (tt / ntx) * 32;
    int x = threadIdx.x, y = threadIdx.y;
    for (int i = 0; i < 32; i += 8)
        tsh[y + i][x] = src[(size_t)(by + y + i) * C + bx + x];
    __syncthreads();
    for (int i = 0; i < 32; i += 8)
        dst[(size_t)(bx + y + i) * R + by + x] = f2bf(tsh[x][y + i]);
}

// ---------------------------------------------------------------------------
// Double-buffered direct-to-LDS K-loop with XOR k-block swizzle.
// global_load_lds forces row-stride 32 u16 (16 banks) -> naive fragment
// ds_read_b128 is 8-way bank conflicted. Fix: staging lane tid loads global
// k-block g = (tid&3) ^ ((tid>>3)&3), so LDS slot kb of row r holds global
// block kb ^ ((r>>1)&3); readers fetch slot quad ^ ((lr>>1)&3). Lanes lr and
// lr+8 alias (2-way = free), all else distinct.
template<int KT>
__device__ __forceinline__ void kloop_db(const u16* __restrict__ Ag, const u16* __restrict__ Bg,
                                         u16* Alds, u16* Blds, f32x4 (&acc)[4][4]) {
    const int tid = threadIdx.x;
    const int wave = tid >> 6, lane = tid & 63;
    const int lr = lane & 15, quad = lane >> 4;
    const int wm = (wave & 1) * 64, wn = (wave >> 1) * 64;
    const int r = tid >> 2;
    const int g8 = (((tid & 3) ^ ((tid >> 3) & 3))) * 8;   // swizzled k-block
    const int kbr8 = (quad ^ ((lr >> 1) & 3)) * 8;         // reader slot
    const u16* ga0 = Ag + (size_t)r * KT + g8;
    const u16* ga1 = ga0 + (size_t)64 * KT;
    const u16* gb0 = Bg + (size_t)r * KT + g8;
    const u16* gb1 = gb0 + (size_t)64 * KT;
    {   // prologue -> buf0
        u16* la = Alds + wave * 512;
        u16* lb = Blds + wave * 512;
        gl_lds16(ga0, la);  gl_lds16(ga1, la + 2048);
        gl_lds16(gb0, lb);  gl_lds16(gb1, lb + 2048);
    }
    #pragma unroll
    for (int k0 = 0; k0 < KT; k0 += 32) {
        const int cur = (k0 >> 5) & 1;
        __syncthreads();   // drains loads into cur; prior-iter LDS reads are consumed
        if (k0 + 32 < KT) {
            u16* la = Alds + (1 - cur) * 4096 + wave * 512;
            u16* lb = Blds + (1 - cur) * 4096 + wave * 512;
            gl_lds16(ga0 + k0 + 32, la);  gl_lds16(ga1 + k0 + 32, la + 2048);
            gl_lds16(gb0 + k0 + 32, lb);  gl_lds16(gb1 + k0 + 32, lb + 2048);
        }
        const u16* Ab = Alds + cur * 4096;
        const u16* Bb = Blds + cur * 4096;
        bh8 af[4], bf_[4];
        #pragma unroll
        for (int i = 0; i < 4; i++) {
            af[i]  = *(const bh8*)&Ab[(wm + i * 16 + lr) * 32 + kbr8];
            bf_[i] = *(const bh8*)&Bb[(wn + i * 16 + lr) * 32 + kbr8];
        }
        #pragma unroll
        for (int mi = 0; mi < 4; mi++)
            #pragma unroll
            for (int ni = 0; ni < 4; ni++)
                acc[mi][ni] = __builtin_amdgcn_mfma_f32_16x16x32_bf16(
                    af[mi], bf_[ni], acc[mi][ni], 0, 0, 0);
    }
}

template<int ACT, int F32OUT>
__device__ __forceinline__ void epilogue(f32x4 (&acc)[4][4], const float* bias,
                                         float* Cf, u16* Cb, int N, int m0, int n0) {
    const int tid = threadIdx.x;
    const int wave = tid >> 6, lane = tid & 63;
    const int lr = lane & 15, quad = lane >> 4;
    const int wm = (wave & 1) * 64, wn = (wave >> 1) * 64;
    #pragma unroll
    for (int ni = 0; ni < 4; ni++) {
        int col = n0 + wn + ni * 16 + lr;
        float bs = bias[col];
        #pragma unroll
        for (int mi = 0; mi < 4; mi++) {
            #pragma unroll
            for (int i = 0; i < 4; i++) {
                int row = m0 + wm + mi * 16 + quad * 4 + i;
                float v = acc[mi][ni][i] + bs;
                if (ACT == 1) v = fmaxf(v, 0.0f);
                if (ACT == 2) v = (v > 0.0f) ? v : 0.01f * v;
                size_t o = (size_t)row * N + col;
                if (F32OUT) Cf[o] = v;
                else        Cb[o] = f2bf(v);
            }
        }
    }
}

template<int ACT, int F32OUT, int KT>
__global__ __launch_bounds__(256) void gemm_gl(
    const u16* __restrict__ A, const u16* __restrict__ B, const float* __restrict__ bias,
    float* __restrict__ Cf, u16* __restrict__ Cb, int N)
{
    __shared__ __align__(16) u16 Alds[2 * 128 * 32];
    __shared__ __align__(16) u16 Blds[2 * 128 * 32];
    const int m0 = blockIdx.y * 128, n0 = blockIdx.x * 128;
    f32x4 acc[4][4] = {};
    kloop_db<KT>(A + (size_t)m0 * KT, B + (size_t)n0 * KT, Alds, Blds, acc);
    epilogue<ACT, F32OUT>(acc, bias, Cf, Cb, N, m0, n0);
}

// fused e_h / e_t
__global__ __launch_bounds__(256) void ehet_gl(
    const u16* __restrict__ A, const u16* __restrict__ Bh, const u16* __restrict__ Bt,
    const float* __restrict__ bh_, const float* __restrict__ bt_,
    u16* __restrict__ Oh, u16* __restrict__ Ot)
{
    __shared__ __align__(16) u16 Alds[2 * 128 * 32];
    __shared__ __align__(16) u16 Blds[2 * 128 * 32];
    const int bx = blockIdx.x;
    const int m0 = blockIdx.y * 128, n0 = (bx & 3) * 128;
    const u16* B = (bx < 4) ? Bh : Bt;
    const float* bias = (bx < 4) ? bh_ : bt_;
    u16* O = (bx < 4) ? Oh : Ot;
    f32x4 acc[4][4] = {};
    kloop_db<512>(A + (size_t)m0 * 512, B + (size_t)n0 * 512, Alds, Blds, acc);
    epilogue<0, 0>(acc, bias, nullptr, O, 512, m0, n0);
}

// fused emb = lrelu(s1@l1+b1) + lrelu(s2@l2+b2)
__global__ __launch_bounds__(256) void lin12_gl(
    const u16* __restrict__ A1, const u16* __restrict__ B1, const float* __restrict__ b1,
    const u16* __restrict__ A2, const u16* __restrict__ B2, const float* __restrict__ b2,
    u16* __restrict__ O)
{
    __shared__ __align__(16) u16 Alds[2 * 128 * 32];
    __shared__ __align__(16) u16 Blds[2 * 128 * 32];
    const int m0 = blockIdx.y * 128, n0 = blockIdx.x * 128;
    f32x4 acc1[4][4] = {}, acc2[4][4] = {};
    kloop_db<512>(A1 + (size_t)m0 * 512, B1 + (size_t)n0 * 512, Alds, Blds, acc1);
    kloop_db<512>(A2 + (size_t)m0 * 512, B2 + (size_t)n0 * 512, Alds, Blds, acc2);
    const int tid = threadIdx.x;
    const int wave = tid >> 6, lane = tid & 63;
    const int lr = lane & 15, quad = lane >> 4;
    const int wm = (wave & 1) * 64, wn = (wave >> 1) * 64;
    #pragma unroll
    for (int ni = 0; ni < 4; ni++) {
        int col = n0 + wn + ni * 16 + lr;
        float bs1 = b1[col], bs2 = b2[col];
        #pragma unroll
        for (int mi = 0; mi < 4; mi++) {
            #pragma unroll
            for (int i = 0; i < 4; i++) {
                int row = m0 + wm + mi * 16 + quad * 4 + i;
                float v1 = acc1[mi][ni][i] + bs1;
                v1 = (v1 > 0.0f) ? v1 : 0.01f * v1;
                float v2 = acc2[mi][ni][i] + bs2;
                v2 = (v2 > 0.0f) ? v2 : 0.01f * v2;
                O[(size_t)row * 512 + col] = f2bf(v1 + v2);
            }
        }
    }
}

// ---------------------------------------------------------------------------
// fused logits GEMM + branchless packed top-6 over a 256-col span. Grid (32,64).
__global__ __launch_bounds__(256) void logits_topk(
    const u16* __restrict__ Ah, const u16* __restrict__ Bt, u32* __restrict__ tvp)
{
    __shared__ __align__(16) u16 Alds[2 * 128 * 32];
    __shared__ __align__(16) u16 Blds[2 * 128 * 32];
    __shared__ u32 S[128 * 65];
    const int tid = threadIdx.x;
    const int m0 = blockIdx.y * 128;
    const int cb0 = blockIdx.x * 256;
    const int lane = tid & 63, wave = tid >> 6;
    const int wm = (wave & 1) * 64, wn = (wave >> 1) * 64;
    const int lr = lane & 15, quad = lane >> 4;
    const int srow = tid >> 1, scg = tid & 1;

    u32 v0 = 0, v1 = 0, v2 = 0, v3 = 0, v4 = 0, v5 = 0;

    for (int nt = 0; nt < 2; nt++) {
        f32x4 acc[4][4] = {};
        kloop_db<512>(Ah + (size_t)m0 * 512,
                      Bt + (size_t)(cb0 + nt * 128) * 512, Alds, Blds, acc);
        #pragma unroll
        for (int half = 0; half < 2; half++) {
            __syncthreads();
            if ((wave >> 1) == half) {
                #pragma unroll
                for (int mi = 0; mi < 4; mi++)
                    #pragma unroll
                    for (int ni = 0; ni < 4; ni++)
                        #pragma unroll
                        for (int i = 0; i < 4; i++) {
                            int colLocal = nt * 128 + half * 64 + ni * 16 + lr;
                            S[(wm + mi * 16 + quad * 4 + i) * 65 + ni * 16 + lr]
                                = pack_vi(acc[mi][ni][i], 255 - colLocal);
                        }
            }
            __syncthreads();
            const u32* Sr = &S[srow * 65 + scg * 32];
            #pragma unroll 8
            for (int c = 0; c < 32; c++) {
                u32 x = Sr[c];
                v5 = max(v5, min(v4, x));
                v4 = max(v4, min(v3, x));
                v3 = max(v3, min(v2, x));
                v2 = max(v2, min(v1, x));
                v1 = max(v1, min(v0, x));
                v0 = max(v0, x);
            }
        }
    }
    __syncthreads();
    {
        u32* dst = &S[srow * 65 + scg * 6];
        dst[0] = v0; dst[1] = v1; dst[2] = v2; dst[3] = v3; dst[4] = v4; dst[5] = v5;
    }
    __syncthreads();
    if (tid < 128) {
        u32 m0v = 0, m1v = 0, m2v = 0, m3v = 0, m4v = 0, m5v = 0;
        const u32* Sr = &S[tid * 65];
        #pragma unroll
        for (int s = 0; s < 12; s++) {
            u32 x = Sr[s];
            m5v = max(m5v, min(m4v, x));
            m4v = max(m4v, min(m3v, x));
            m3v = max(m3v, min(m2v, x));
            m2v = max(m2v, min(m1v, x));
            m1v = max(m1v, min(m0v, x));
            m0v = max(m0v, x);
        }
        u32* dst = tvp + (size_t)(m0 + tid) * 192 + blockIdx.x * 6;
        dst[0] = m0v; dst[1] = m1v; dst[2] = m2v;
        dst[3] = m3v; dst[4] = m4v; dst[5] = m5v;
    }
}

// merge 32 packed partial top-6 lists per row -> final top-6 (fp32 val + idx)
__global__ void topk_merge(const u32* __restrict__ tvp,
                           float* __restrict__ tv, int* __restrict__ ti)
{
    int r = blockIdx.x * 64 + threadIdx.x;
    u32 v[6]; int ix[6];
    #pragma unroll
    for (int j = 0; j < 6; j++) { v[j] = 0; ix[j] = 0; }
    const u32* pv = tvp + (size_t)r * 192;
    for (int b = 0; b < 32; b++) {
        #pragma unroll
        for (int j2 = 0; j2 < 6; j2++) {
            u32 p = pv[b * 6 + j2];
            if (p <= v[5]) break;     // group is descending: rest can't insert
            v[5] = p; ix[5] = b * 256 + 255 - (int)(p & 255u);
            #pragma unroll
            for (int j = 5; j > 0; j--) {
                if (v[j] > v[j - 1]) {
                    u32 tf = v[j]; v[j] = v[j - 1]; v[j - 1] = tf;
                    int tx = ix[j]; ix[j] = ix[j - 1]; ix[j - 1] = tx;
                }
            }
        }
    }
    #pragma unroll
    for (int j = 0; j < 6; j++) {
        tv[(size_t)r * 6 + j] = unpack_v(v[j]) * SCALE_F;
        ti[(size_t)r * 6 + j] = ix[j];
    }
}

// ---------------------------------------------------------------------------
// neighbor aggregation, one WAVE per row (no block barriers). fp32 math.
__global__ __launch_bounds__(256) void neighbor_kernel(
    const u16* __restrict__ eH, const u16* __restrict__ eT,
    const float* __restrict__ tv, const int* __restrict__ ti,
    u16* __restrict__ s1, u16* __restrict__ s2)
{
    const int tid = threadIdx.x, wave = tid >> 6, lane = tid & 63;
    const int n = blockIdx.x * 4 + wave;
    float tw[6]; int id[6];
    #pragma unroll
    for (int j = 0; j < 6; j++) {
        tw[j] = tv[n * 6 + j];
        int t = ti[n * 6 + j];
        id[j] = ((unsigned)t < 8192u) ? t : 0;
    }
    float mx = tw[0];
    #pragma unroll
    for (int j = 1; j < 6; j++) mx = fmaxf(mx, tw[j]);
    float p[6]; float ps = 0.f;
    #pragma unroll
    for (int j = 0; j < 6; j++) { p[j] = __expf(tw[j] - mx); ps += p[j]; }
    float inv = 1.0f / ps;
    #pragma unroll
    for (int j = 0; j < 6; j++) p[j] *= inv;

    const size_t base = (size_t)n * 512 + lane * 8;
    float eh[8];
    { bh8 v = *(const bh8*)(eH + base);
      #pragma unroll
      for (int c = 0; c < 8; c++) eh[c] = (float)v[c]; }
    float nb[6][8];
    #pragma unroll
    for (int j = 0; j < 6; j++) {
        bh8 v = *(const bh8*)(eT + (size_t)id[j] * 512 + lane * 8);
        #pragma unroll
        for (int c = 0; c < 8; c++) nb[j][c] = (float)v[c];
    }
    float ka[6];
    #pragma unroll
    for (int j = 0; j < 6; j++) {
        float s = 0.f;
        #pragma unroll
        for (int c = 0; c < 8; c++) {
            float e = p[j] * nb[j][c] + (1.f - p[j]) * eh[c];
            float x = eh[c] + e;
            x = fminf(fmaxf(x, -15.f), 15.f);
            float ex = __expf(2.f * x);
            float g = 1.f - 2.f / (ex + 1.f);   // tanh
            s += nb[j][c] * g;
        }
        #pragma unroll
        for (int off = 32; off > 0; off >>= 1) s += __shfl_down(s, off);
        ka[j] = __shfl(s, 0);
    }
    float m2 = ka[0];
    #pragma unroll
    for (int j = 1; j < 6; j++) m2 = fmaxf(m2, ka[j]);
    float kp[6]; float ks = 0.f;
    #pragma unroll
    for (int j = 0; j < 6; j++) { kp[j] = __expf(ka[j] - m2); ks += kp[j]; }
    float inv2 = 1.0f / ks;
    #pragma unroll
    for (int j = 0; j < 6; j++) kp[j] *= inv2;
    bh8 o1, o2;
    #pragma unroll
    for (int c = 0; c < 8; c++) {
        float eN = 0.f;
        #pragma unroll
        for (int j = 0; j < 6; j++) eN += kp[j] * nb[j][c];
        o1[c] = (bh)(eh[c] + eN);
        o2[c] = (bh)(eh[c] * eN);
    }
    *(bh8*)(s1 + base) = o1;
    *(bh8*)(s2 + base) = o2;
}

// ---------------------------------------------------------------------------
__global__ void colsum_kernel(const u16* __restrict__ h, float* __restrict__ colsum) {
    int tid = threadIdx.x;
    int n0 = blockIdx.x * 32;
    float a0 = 0.f, a1 = 0.f;
    for (int k = 0; k < 32; k++) {
        size_t b = (size_t)(n0 + k) * 512;
        a0 += bf2f(h[b + tid]); a1 += bf2f(h[b + tid + 256]);
    }
    atomicAdd(&colsum[tid], a0);
    atomicAdd(&colsum[tid + 256], a1);
}

__global__ void meanmix_kernel(u16* __restrict__ h, const float* __restrict__ colsum) {
    size_t i = ((size_t)blockIdx.x * 256 + threadIdx.x) * 8;
    int col = (int)(i & 511);
    union { int4 v; u16 s[8]; } u;
    u.v = *(const int4*)&h[i];
    #pragma unroll
    for (int j = 0; j < 8; j++)
        u.s[j] = f2bf((bf2f(u.s[j]) + colsum[col + j] * (1.0f / 8192.0f)) * 0.5f);
    *(int4*)&h[i] = u.v;
}

__global__ __launch_bounds__(256) void att2_kernel(
    const float* __restrict__ a1, const float* __restrict__ w,
    const float* __restrict__ b, float* __restrict__ att)
{
    int row = blockIdx.x * 4 + (threadIdx.x >> 6);
    int lane = threadIdx.x & 63;
    const float* pr = a1 + (size_t)row * 256;
    float s = 0.f;
    #pragma unroll
    for (int k = 0; k < 4; k++) { int c = lane + k * 64; s += pr[c] * w[c]; }
    #pragma unroll
    for (int off = 32; off > 0; off >>= 1) s += __shfl_down(s, off);
    if (lane == 0) att[row] = s + b[0];
}

// parallel softmax stats: ordered-u32 atomicMax, then atomicAdd of exp sums
__global__ void att_max(const float* __restrict__ att, u32* __restrict__ scal_u) {
    int i = blockIdx.x * 256 + threadIdx.x;
    int lane = threadIdx.x & 63;
    u32 o = ordf(att[i]);
    #pragma unroll
    for (int off = 32; off > 0; off >>= 1) o = max(o, (u32)__shfl_down((int)o, off));
    if (lane == 0) atomicMax(&scal_u[0], o);
}
__global__ void att_sum(const float* __restrict__ att, float* __restrict__ scal) {
    int i = blockIdx.x * 256 + threadIdx.x;
    int lane = threadIdx.x & 63;
    float mx = unordf(((const u32*)scal)[0]);
    float e = __expf(att[i] - mx);
    #pragma unroll
    for (int off = 32; off > 0; off >>= 1) e += __shfl_down(e, off);
    if (lane == 0) atomicAdd(&scal[1], e);
}

__global__ void pooled_kernel(const u16* __restrict__ emb, const float* __restrict__ att,
                              const float* __restrict__ scal, float* __restrict__ pooled) {
    int tid = threadIdx.x;
    int n0 = blockIdx.x * 32;
    float mx = unordf(((const u32*)scal)[0]);
    float inv = 1.0f / scal[1];
    float a0 = 0.f, a1 = 0.f;
    for (int k = 0; k < 32; k++) {
        int n = n0 + k;
        float w = __expf(att[n] - mx) * inv;
        size_t b = (size_t)n * 512;
        a0 += w * bf2f(emb[b + tid]);
        a1 += w * bf2f(emb[b + tid + 256]);
    }
    atomicAdd(&pooled[tid], a0);
    atomicAdd(&pooled[tid + 256], a1);
}

__global__ void final_kernel(const float* __restrict__ pooled,
                             const float* __restrict__ g, const float* __restrict__ bln,
                             const float* __restrict__ fcw, const float* __restrict__ fcb,
                             float* __restrict__ out) {
    __shared__ float red[256];
    int tid = threadIdx.x;
    float x0 = pooled[tid], x1 = pooled[tid + 256];
    red[tid] = x0 + x1; __syncthreads();
    for (int s = 128; s > 0; s >>= 1) { if (tid < s) red[tid] += red[tid + s]; __syncthreads(); }
    float mu = red[0] * (1.0f / 512.0f); __syncthreads();
    float d0 = x0 - mu, d1 = x1 - mu;
    red[tid] = d0 * d0 + d1 * d1; __syncthreads();
    for (int s = 128; s > 0; s >>= 1) { if (tid < s) red[tid] += red[tid + s]; __syncthreads(); }
    float var = red[0] * (1.0f / 512.0f); __syncthreads();
    float rstd = rsqrtf(var + 1e-5f);
    float l0 = d0 * rstd * g[tid]       + bln[tid];
    float l1 = d1 * rstd * g[tid + 256] + bln[tid + 256];
    red[tid] = l0 * fcw[tid * 2] + l1 * fcw[(tid + 256) * 2]; __syncthreads();
    for (int s = 128; s > 0; s >>= 1) { if (tid < s) red[tid] += red[tid + s]; __syncthreads(); }
    float o0 = red[0] + fcb[0]; __syncthreads();
    red[tid] = l0 * fcw[tid * 2 + 1] + l1 * fcw[(tid + 256) * 2 + 1]; __syncthreads();
    for (int s = 128; s > 0; s >>= 1) { if (tid < s) red[tid] += red[tid + s]; __syncthreads(); }
    float o1 = red[0] + fcb[1];
    if (tid == 0) {
        float m = fmaxf(o0, o1);
        float e0 = expf(o0 - m), e1 = expf(o1 - m);
        float se = e0 + e1;
        out[0] = o0;
        out[1] = o1;
        out[2] = e0 / se;
        out[3] = e1 / se;
        out[4] = (o0 >= o1) ? 0.0f : 1.0f;
    }
}

// ---------------------------------------------------------------------------
extern "C" void kernel_launch(void* const* d_in, const int* in_sizes, int n_in,
                              void* d_out, int out_size, void* d_ws, size_t ws_size,
                              hipStream_t stream)
{
    const float* x      = (const float*)d_in[0];
    const float* fc1_w  = (const float*)d_in[1];
    const float* fc1_b  = (const float*)d_in[2];
    const float* wh_w   = (const float*)d_in[3];
    const float* wh_b   = (const float*)d_in[4];
    const float* wt_w   = (const float*)d_in[5];
    const float* wt_b   = (const float*)d_in[6];
    const float* lin1_w = (const float*)d_in[7];
    const float* lin1_b = (const float*)d_in[8];
    const float* lin2_w = (const float*)d_in[9];
    const float* lin2_b = (const float*)d_in[10];
    const float* att1_w = (const float*)d_in[11];
    const float* att1_b = (const float*)d_in[12];
    const float* att2_w = (const float*)d_in[13];
    const float* att2_b = (const float*)d_in[14];
    const float* ln_g   = (const float*)d_in[15];
    const float* ln_b   = (const float*)d_in[16];
    const float* fc_w   = (const float*)d_in[17];
    const float* fc_b   = (const float*)d_in[18];
    float* out = (float*)d_out;
    char* ws = (char*)d_ws;

    u16*   fc1T   = (u16*)(ws + 0);
    u16*   whT    = (u16*)(ws + 1048576);
    u16*   wtT    = (u16*)(ws + 1572864);
    u16*   l1T    = (u16*)(ws + 2097152);
    u16*   l2T    = (u16*)(ws + 2621440);
    u16*   a1T    = (u16*)(ws + 3145728);
    float* tv     = (float*)(ws + 3407872);
    int*   ti     = (int*)(ws + 3604480);
    float* att    = (float*)(ws + 3801088);
    float* colsum = (float*)(ws + 3833856);
    float* pooled = (float*)(ws + 3835904);
    float* scal   = (float*)(ws + 3837952);
    u32*   tvp    = (u32*)(ws + 4194304);
    u16*   hbf    = (u16*)(ws + 14680064);   // 8 MB  [h; later s1]
    u16*   ehbf   = (u16*)(ws + 23068672);   // 8 MB  [e_h; later a1 fp32]
    u16*   etbf   = (u16*)(ws + 31457280);   // 8 MB  [e_t; later emb]
    u16*   s2bf   = (u16*)(ws + 39845888);   // 8 MB  [s2]
    u16*   xbf    = (u16*)(ws + 23068672);   // 16 MB (x bf16; dead after fc1)
    float* a1f    = (float*)(ws + 23068672); // 8 MB fp32 (after e_h dead)

    transpose_cvt<<<5760, dim3(32, 8), 0, stream>>>(
        fc1_w, fc1T, wh_w, whT, wt_w, wtT, lin1_w, l1T, lin2_w, l2T, att1_w, a1T, x, xbf);
    hipMemsetAsync(colsum, 0, 4160, stream);   // colsum + pooled + scal

    gemm_gl<1, 0, 1024><<<dim3(4, 64), 256, 0, stream>>>(xbf, fc1T, fc1_b, nullptr, hbf, 512);
    colsum_kernel<<<256, 256, 0, stream>>>(hbf, colsum);
    meanmix_kernel<<<2048, 256, 0, stream>>>(hbf, colsum);

    ehet_gl<<<dim3(8, 64), 256, 0, stream>>>(hbf, whT, wtT, wh_b, wt_b, ehbf, etbf);

    logits_topk<<<dim3(32, 64), 256, 0, stream>>>(ehbf, etbf, tvp);
    topk_merge<<<128, 64, 0, stream>>>(tvp, tv, ti);

    neighbor_kernel<<<2048, 256, 0, stream>>>(ehbf, etbf, tv, ti, hbf, s2bf);

    lin12_gl<<<dim3(4, 64), 256, 0, stream>>>(hbf, l1T, lin1_b, s2bf, l2T, lin2_b, etbf);

    gemm_gl<2, 1, 512><<<dim3(2, 64), 256, 0, stream>>>(etbf, a1T, att1_b, a1f, nullptr, 256);
    att2_kernel<<<2048, 256, 0, stream>>>(a1f, att2_w, att2_b, att);
    att_max<<<32, 256, 0, stream>>>(att, (u32*)scal);
    att_sum<<<32, 256, 0, stream>>>(att, scal);
    pooled_kernel<<<256, 256, 0, stream>>>(etbf, att, scal, pooled);

    final_kernel<<<1, 256, 0, stream>>>(pooled, ln_g, ln_b, fc_w, fc_b, out);
}

// Round 9
// 434.222 us; speedup vs baseline: 1.0552x; 1.0552x over previous
//
#include <hip/hip_runtime.h>
#include <hip/hip_bf16.h>
#include <cstdint>
#include <math.h>

typedef unsigned short u16;
typedef unsigned int u32;
typedef __bf16 bh;
typedef bh bh8 __attribute__((ext_vector_type(8)));
typedef float f32x4 __attribute__((ext_vector_type(4)));

#define SCALE_F 0.04419417382415922f  // 512^-0.5

__device__ __forceinline__ float bf2f(u16 u) {
    union { float f; unsigned int i; } v; v.i = ((unsigned int)u) << 16; return v.f;
}
__device__ __forceinline__ u16 f2bf(float f) {
    __hip_bfloat16 h = __float2bfloat16(f);
    return __builtin_bit_cast(u16, h);
}
__device__ __forceinline__ bh8 ld8_f32(const float* p) {
    float4 f0 = *(const float4*)p;
    float4 f1 = *(const float4*)(p + 4);
    bh8 r;
    r[0] = (bh)f0.x; r[1] = (bh)f0.y; r[2] = (bh)f0.z; r[3] = (bh)f0.w;
    r[4] = (bh)f1.x; r[5] = (bh)f1.y; r[6] = (bh)f1.z; r[7] = (bh)f1.w;
    return r;
}

// ordered-uint transforms (monotone with float order)
__device__ __forceinline__ u32 ordf(float f) {
    u32 u = __float_as_uint(f);
    return u ^ ((u32)((int)u >> 31) | 0x80000000u);
}
__device__ __forceinline__ float unordf(u32 s) {
    u32 u = (s & 0x80000000u) ? (s ^ 0x80000000u) : ~s;
    return __uint_as_float(u);
}
// 24-bit ordered value | 8-bit inverted local col idx (tie -> smaller idx wins)
__device__ __forceinline__ u32 pack_vi(float v, int inv_idx) {
    return (ordf(v) & 0xFFFFFF00u) | (u32)inv_idx;
}
__device__ __forceinline__ float unpack_v(u32 p) {
    return unordf(p & 0xFFFFFF00u);
}

// direct global->LDS 16B per lane; lds base wave-uniform (dest = base + lane*16)
__device__ __forceinline__ void gl_lds16(const u16* g, u16* l) {
    __builtin_amdgcn_global_load_lds(
        (const __attribute__((address_space(1))) void*)g,
        (__attribute__((address_space(3))) void*)l, 16, 0, 0);
}

// ---------------------------------------------------------------------------
// 6 weight transposes (fp32 [R,C] -> bf16 [C,R]) + x fp32->bf16, one dispatch
__global__ void transpose_cvt(const float* s0, u16* d0, const float* s1, u16* d1,
                              const float* s2, u16* d2, const float* s3, u16* d3,
                              const float* s4, u16* d4, const float* s5, u16* d5,
                              const float* xs, u16* xd) {
    int b = blockIdx.x;
    if (b >= 1664) {  // cvt_x part: 4096 blocks, 8 elems/thread
        int t = threadIdx.y * 32 + threadIdx.x;
        size_t i = ((size_t)(b - 1664) * 256 + t) * 8;
        *(bh8*)(xd + i) = ld8_f32(xs + i);
        return;
    }
    __shared__ float tsh[32][33];
    const float* src; u16* dst; int R, C, tt;
    if      (b < 512)  { src = s0; dst = d0; R = 1024; C = 512; tt = b; }
    else if (b < 768)  { src = s1; dst = d1; R = 512;  C = 512; tt = b - 512; }
    else if (b < 1024) { src = s2; dst = d2; R = 512;  C = 512; tt = b - 768; }
    else if (b < 1280) { src = s3; dst = d3; R = 512;  C = 512; tt = b - 1024; }
    else if (b < 1536) { src = s4; dst = d4; R = 512;  C = 512; tt = b - 1280; }
    else               { src = s5; dst = d5; R = 512;  C = 256; tt = b - 1536; }
    int ntx = C >> 5;
    int bx = (tt % ntx) * 32, by = (tt / ntx) * 32;
    int x = threadIdx.x, y = threadIdx.y;
    for (int i = 0; i < 32; i += 8)
        tsh[y + i][x] = src[(size_t)(by + y + i) * C + bx + x];
    __syncthreads();
    for (int i = 0; i < 32; i += 8)
        dst[(size_t)(bx + y + i) * R + by + x] = f2bf(tsh[x][y + i]);
}

// ---------------------------------------------------------------------------
// Single-buffered direct-to-LDS K-loop with XOR k-block swizzle (conflict fix
// verified R8: SQ_LDS_BANK_CONFLICT 12.7M -> 4.3M). Staging lane tid loads
// global k-block g = (tid&3)^((tid>>3)&3); readers fetch slot quad^((lr>>1)&3).
// Alds/Blds are 128*32 u16 (8KB each) -> small LDS for high block residency.
template<int KT>
__device__ __forceinline__ void kloop_sb(const u16* __restrict__ Ag, const u16* __restrict__ Bg,
                                         u16* Alds, u16* Blds, f32x4 (&acc)[4][4]) {
    const int tid = threadIdx.x;
    const int wave = tid >> 6, lane = tid & 63;
    const int lr = lane & 15, quad = lane >> 4;
    const int wm = (wave & 1) * 64, wn = (wave >> 1) * 64;
    const int r = tid >> 2;
    const int g8 = (((tid & 3) ^ ((tid >> 3) & 3))) * 8;   // swizzled k-block
    const int kbr8 = (quad ^ ((lr >> 1) & 3)) * 8;         // reader slot
    const u16* ga0 = Ag + (size_t)r * KT + g8;
    const u16* ga1 = ga0 + (size_t)64 * KT;
    const u16* gb0 = Bg + (size_t)r * KT + g8;
    const u16* gb1 = gb0 + (size_t)64 * KT;
    u16* la = Alds + wave * 512;   // wave-uniform
    u16* lb = Blds + wave * 512;
    #pragma unroll
    for (int k0 = 0; k0 < KT; k0 += 32) {
        __syncthreads();                 // prior reads done before LDS overwrite
        gl_lds16(ga0 + k0, la);
        gl_lds16(ga1 + k0, la + 2048);   // rows 64..127
        gl_lds16(gb0 + k0, lb);
        gl_lds16(gb1 + k0, lb + 2048);
        __syncthreads();                 // drains vmcnt -> LDS writes visible
        bh8 af[4], bf_[4];
        #pragma unroll
        for (int i = 0; i < 4; i++) {
            af[i]  = *(const bh8*)&Alds[(wm + i * 16 + lr) * 32 + kbr8];
            bf_[i] = *(const bh8*)&Blds[(wn + i * 16 + lr) * 32 + kbr8];
        }
        #pragma unroll
        for (int mi = 0; mi < 4; mi++)
            #pragma unroll
            for (int ni = 0; ni < 4; ni++)
                acc[mi][ni] = __builtin_amdgcn_mfma_f32_16x16x32_bf16(
                    af[mi], bf_[ni], acc[mi][ni], 0, 0, 0);
    }
}

template<int ACT, int F32OUT>
__device__ __forceinline__ void epilogue(f32x4 (&acc)[4][4], const float* bias,
                                         float* Cf, u16* Cb, int N, int m0, int n0) {
    const int tid = threadIdx.x;
    const int wave = tid >> 6, lane = tid & 63;
    const int lr = lane & 15, quad = lane >> 4;
    const int wm = (wave & 1) * 64, wn = (wave >> 1) * 64;
    #pragma unroll
    for (int ni = 0; ni < 4; ni++) {
        int col = n0 + wn + ni * 16 + lr;
        float bs = bias[col];
        #pragma unroll
        for (int mi = 0; mi < 4; mi++) {
            #pragma unroll
            for (int i = 0; i < 4; i++) {
                int row = m0 + wm + mi * 16 + quad * 4 + i;
                float v = acc[mi][ni][i] + bs;
                if (ACT == 1) v = fmaxf(v, 0.0f);
                if (ACT == 2) v = (v > 0.0f) ? v : 0.01f * v;
                size_t o = (size_t)row * N + col;
                if (F32OUT) Cf[o] = v;
                else        Cb[o] = f2bf(v);
            }
        }
    }
}

template<int ACT, int F32OUT, int KT>
__global__ __launch_bounds__(256, 4) void gemm_gl(
    const u16* __restrict__ A, const u16* __restrict__ B, const float* __restrict__ bias,
    float* __restrict__ Cf, u16* __restrict__ Cb, int N)
{
    __shared__ __align__(16) u16 Alds[128 * 32];
    __shared__ __align__(16) u16 Blds[128 * 32];
    const int m0 = blockIdx.y * 128, n0 = blockIdx.x * 128;
    f32x4 acc[4][4] = {};
    kloop_sb<KT>(A + (size_t)m0 * KT, B + (size_t)n0 * KT, Alds, Blds, acc);
    epilogue<ACT, F32OUT>(acc, bias, Cf, Cb, N, m0, n0);
}

// fused e_h / e_t
__global__ __launch_bounds__(256, 4) void ehet_gl(
    const u16* __restrict__ A, const u16* __restrict__ Bh, const u16* __restrict__ Bt,
    const float* __restrict__ bh_, const float* __restrict__ bt_,
    u16* __restrict__ Oh, u16* __restrict__ Ot)
{
    __shared__ __align__(16) u16 Alds[128 * 32];
    __shared__ __align__(16) u16 Blds[128 * 32];
    const int bx = blockIdx.x;
    const int m0 = blockIdx.y * 128, n0 = (bx & 3) * 128;
    const u16* B = (bx < 4) ? Bh : Bt;
    const float* bias = (bx < 4) ? bh_ : bt_;
    u16* O = (bx < 4) ? Oh : Ot;
    f32x4 acc[4][4] = {};
    kloop_sb<512>(A + (size_t)m0 * 512, B + (size_t)n0 * 512, Alds, Blds, acc);
    epilogue<0, 0>(acc, bias, nullptr, O, 512, m0, n0);
}

// fused emb = lrelu(s1@l1+b1) + lrelu(s2@l2+b2)
__global__ __launch_bounds__(256, 3) void lin12_gl(
    const u16* __restrict__ A1, const u16* __restrict__ B1, const float* __restrict__ b1,
    const u16* __restrict__ A2, const u16* __restrict__ B2, const float* __restrict__ b2,
    u16* __restrict__ O)
{
    __shared__ __align__(16) u16 Alds[128 * 32];
    __shared__ __align__(16) u16 Blds[128 * 32];
    const int m0 = blockIdx.y * 128, n0 = blockIdx.x * 128;
    f32x4 acc1[4][4] = {}, acc2[4][4] = {};
    kloop_sb<512>(A1 + (size_t)m0 * 512, B1 + (size_t)n0 * 512, Alds, Blds, acc1);
    kloop_sb<512>(A2 + (size_t)m0 * 512, B2 + (size_t)n0 * 512, Alds, Blds, acc2);
    const int tid = threadIdx.x;
    const int wave = tid >> 6, lane = tid & 63;
    const int lr = lane & 15, quad = lane >> 4;
    const int wm = (wave & 1) * 64, wn = (wave >> 1) * 64;
    #pragma unroll
    for (int ni = 0; ni < 4; ni++) {
        int col = n0 + wn + ni * 16 + lr;
        float bs1 = b1[col], bs2 = b2[col];
        #pragma unroll
        for (int mi = 0; mi < 4; mi++) {
            #pragma unroll
            for (int i = 0; i < 4; i++) {
                int row = m0 + wm + mi * 16 + quad * 4 + i;
                float v1 = acc1[mi][ni][i] + bs1;
                v1 = (v1 > 0.0f) ? v1 : 0.01f * v1;
                float v2 = acc2[mi][ni][i] + bs2;
                v2 = (v2 > 0.0f) ? v2 : 0.01f * v2;
                O[(size_t)row * 512 + col] = f2bf(v1 + v2);
            }
        }
    }
}

// ---------------------------------------------------------------------------
// fused logits GEMM + branchless packed top-6 over a 256-col span. Grid (32,64).
// LDS = 8K + 8K + 33.3K = 49.7KB -> 3 blocks/CU; VGPR capped via
// __launch_bounds__(256,3) (<=170) so VGPR doesn't bind below 3 blocks.
__global__ __launch_bounds__(256, 3) void logits_topk(
    const u16* __restrict__ Ah, const u16* __restrict__ Bt, u32* __restrict__ tvp)
{
    __shared__ __align__(16) u16 Alds[128 * 32];
    __shared__ __align__(16) u16 Blds[128 * 32];
    __shared__ u32 S[128 * 65];
    const int tid = threadIdx.x;
    const int m0 = blockIdx.y * 128;
    const int cb0 = blockIdx.x * 256;
    const int lane = tid & 63, wave = tid >> 6;
    const int wm = (wave & 1) * 64, wn = (wave >> 1) * 64;
    const int lr = lane & 15, quad = lane >> 4;
    const int srow = tid >> 1, scg = tid & 1;

    u32 v0 = 0, v1 = 0, v2 = 0, v3 = 0, v4 = 0, v5 = 0;

    for (int nt = 0; nt < 2; nt++) {
        f32x4 acc[4][4] = {};
        kloop_sb<512>(Ah + (size_t)m0 * 512,
                      Bt + (size_t)(cb0 + nt * 128) * 512, Alds, Blds, acc);
        #pragma unroll
        for (int half = 0; half < 2; half++) {
            __syncthreads();
            if ((wave >> 1) == half) {
                #pragma unroll
                for (int mi = 0; mi < 4; mi++)
                    #pragma unroll
                    for (int ni = 0; ni < 4; ni++)
                        #pragma unroll
                        for (int i = 0; i < 4; i++) {
                            int colLocal = nt * 128 + half * 64 + ni * 16 + lr;
                            S[(wm + mi * 16 + quad * 4 + i) * 65 + ni * 16 + lr]
                                = pack_vi(acc[mi][ni][i], 255 - colLocal);
                        }
            }
            __syncthreads();
            const u32* Sr = &S[srow * 65 + scg * 32];
            #pragma unroll 8
            for (int c = 0; c < 32; c++) {
                u32 x = Sr[c];
                v5 = max(v5, min(v4, x));
                v4 = max(v4, min(v3, x));
                v3 = max(v3, min(v2, x));
                v2 = max(v2, min(v1, x));
                v1 = max(v1, min(v0, x));
                v0 = max(v0, x);
            }
        }
    }
    __syncthreads();
    {
        u32* dst = &S[srow * 65 + scg * 6];
        dst[0] = v0; dst[1] = v1; dst[2] = v2; dst[3] = v3; dst[4] = v4; dst[5] = v5;
    }
    __syncthreads();
    if (tid < 128) {
        u32 m0v = 0, m1v = 0, m2v = 0, m3v = 0, m4v = 0, m5v = 0;
        const u32* Sr = &S[tid * 65];
        #pragma unroll
        for (int s = 0; s < 12; s++) {
            u32 x = Sr[s];
            m5v = max(m5v, min(m4v, x));
            m4v = max(m4v, min(m3v, x));
            m3v = max(m3v, min(m2v, x));
            m2v = max(m2v, min(m1v, x));
            m1v = max(m1v, min(m0v, x));
            m0v = max(m0v, x);
        }
        u32* dst = tvp + (size_t)(m0 + tid) * 192 + blockIdx.x * 6;
        dst[0] = m0v; dst[1] = m1v; dst[2] = m2v;
        dst[3] = m3v; dst[4] = m4v; dst[5] = m5v;
    }
}

// merge 32 packed partial top-6 lists per row -> final top-6 (fp32 val + idx)
__global__ void topk_merge(const u32* __restrict__ tvp,
                           float* __restrict__ tv, int* __restrict__ ti)
{
    int r = blockIdx.x * 64 + threadIdx.x;
    u32 v[6]; int ix[6];
    #pragma unroll
    for (int j = 0; j < 6; j++) { v[j] = 0; ix[j] = 0; }
    const u32* pv = tvp + (size_t)r * 192;
    for (int b = 0; b < 32; b++) {
        #pragma unroll
        for (int j2 = 0; j2 < 6; j2++) {
            u32 p = pv[b * 6 + j2];
            if (p <= v[5]) break;     // group is descending: rest can't insert
            v[5] = p; ix[5] = b * 256 + 255 - (int)(p & 255u);
            #pragma unroll
            for (int j = 5; j > 0; j--) {
                if (v[j] > v[j - 1]) {
                    u32 tf = v[j]; v[j] = v[j - 1]; v[j - 1] = tf;
                    int tx = ix[j]; ix[j] = ix[j - 1]; ix[j - 1] = tx;
                }
            }
        }
    }
    #pragma unroll
    for (int j = 0; j < 6; j++) {
        tv[(size_t)r * 6 + j] = unpack_v(v[j]) * SCALE_F;
        ti[(size_t)r * 6 + j] = ix[j];
    }
}

// ---------------------------------------------------------------------------
// neighbor aggregation, one WAVE per row (no block barriers). fp32 math.
__global__ __launch_bounds__(256) void neighbor_kernel(
    const u16* __restrict__ eH, const u16* __restrict__ eT,
    const float* __restrict__ tv, const int* __restrict__ ti,
    u16* __restrict__ s1, u16* __restrict__ s2)
{
    const int tid = threadIdx.x, wave = tid >> 6, lane = tid & 63;
    const int n = blockIdx.x * 4 + wave;
    float tw[6]; int id[6];
    #pragma unroll
    for (int j = 0; j < 6; j++) {
        tw[j] = tv[n * 6 + j];
        int t = ti[n * 6 + j];
        id[j] = ((unsigned)t < 8192u) ? t : 0;
    }
    float mx = tw[0];
    #pragma unroll
    for (int j = 1; j < 6; j++) mx = fmaxf(mx, tw[j]);
    float p[6]; float ps = 0.f;
    #pragma unroll
    for (int j = 0; j < 6; j++) { p[j] = __expf(tw[j] - mx); ps += p[j]; }
    float inv = 1.0f / ps;
    #pragma unroll
    for (int j = 0; j < 6; j++) p[j] *= inv;

    const size_t base = (size_t)n * 512 + lane * 8;
    float eh[8];
    { bh8 v = *(const bh8*)(eH + base);
      #pragma unroll
      for (int c = 0; c < 8; c++) eh[c] = (float)v[c]; }
    float nb[6][8];
    #pragma unroll
    for (int j = 0; j < 6; j++) {
        bh8 v = *(const bh8*)(eT + (size_t)id[j] * 512 + lane * 8);
        #pragma unroll
        for (int c = 0; c < 8; c++) nb[j][c] = (float)v[c];
    }
    float ka[6];
    #pragma unroll
    for (int j = 0; j < 6; j++) {
        float s = 0.f;
        #pragma unroll
        for (int c = 0; c < 8; c++) {
            float e = p[j] * nb[j][c] + (1.f - p[j]) * eh[c];
            float x = eh[c] + e;
            x = fminf(fmaxf(x, -15.f), 15.f);
            float ex = __expf(2.f * x);
            float g = 1.f - 2.f / (ex + 1.f);   // tanh
            s += nb[j][c] * g;
        }
        #pragma unroll
        for (int off = 32; off > 0; off >>= 1) s += __shfl_down(s, off);
        ka[j] = __shfl(s, 0);
    }
    float m2 = ka[0];
    #pragma unroll
    for (int j = 1; j < 6; j++) m2 = fmaxf(m2, ka[j]);
    float kp[6]; float ks = 0.f;
    #pragma unroll
    for (int j = 0; j < 6; j++) { kp[j] = __expf(ka[j] - m2); ks += kp[j]; }
    float inv2 = 1.0f / ks;
    #pragma unroll
    for (int j = 0; j < 6; j++) kp[j] *= inv2;
    bh8 o1, o2;
    #pragma unroll
    for (int c = 0; c < 8; c++) {
        float eN = 0.f;
        #pragma unroll
        for (int j = 0; j < 6; j++) eN += kp[j] * nb[j][c];
        o1[c] = (bh)(eh[c] + eN);
        o2[c] = (bh)(eh[c] * eN);
    }
    *(bh8*)(s1 + base) = o1;
    *(bh8*)(s2 + base) = o2;
}

// ---------------------------------------------------------------------------
__global__ void colsum_kernel(const u16* __restrict__ h, float* __restrict__ colsum) {
    int tid = threadIdx.x;
    int n0 = blockIdx.x * 32;
    float a0 = 0.f, a1 = 0.f;
    for (int k = 0; k < 32; k++) {
        size_t b = (size_t)(n0 + k) * 512;
        a0 += bf2f(h[b + tid]); a1 += bf2f(h[b + tid + 256]);
    }
    atomicAdd(&colsum[tid], a0);
    atomicAdd(&colsum[tid + 256], a1);
}

__global__ void meanmix_kernel(u16* __restrict__ h, const float* __restrict__ colsum) {
    size_t i = ((size_t)blockIdx.x * 256 + threadIdx.x) * 8;
    int col = (int)(i & 511);
    union { int4 v; u16 s[8]; } u;
    u.v = *(const int4*)&h[i];
    #pragma unroll
    for (int j = 0; j < 8; j++)
        u.s[j] = f2bf((bf2f(u.s[j]) + colsum[col + j] * (1.0f / 8192.0f)) * 0.5f);
    *(int4*)&h[i] = u.v;
}

__global__ __launch_bounds__(256) void att2_kernel(
    const float* __restrict__ a1, const float* __restrict__ w,
    const float* __restrict__ b, float* __restrict__ att)
{
    int row = blockIdx.x * 4 + (threadIdx.x >> 6);
    int lane = threadIdx.x & 63;
    const float* pr = a1 + (size_t)row * 256;
    float s = 0.f;
    #pragma unroll
    for (int k = 0; k < 4; k++) { int c = lane + k * 64; s += pr[c] * w[c]; }
    #pragma unroll
    for (int off = 32; off > 0; off >>= 1) s += __shfl_down(s, off);
    if (lane == 0) att[row] = s + b[0];
}

// parallel softmax stats: ordered-u32 atomicMax, then atomicAdd of exp sums
__global__ void att_max(const float* __restrict__ att, u32* __restrict__ scal_u) {
    int i = blockIdx.x * 256 + threadIdx.x;
    int lane = threadIdx.x & 63;
    u32 o = ordf(att[i]);
    #pragma unroll
    for (int off = 32; off > 0; off >>= 1) o = max(o, (u32)__shfl_down((int)o, off));
    if (lane == 0) atomicMax(&scal_u[0], o);
}
__global__ void att_sum(const float* __restrict__ att, float* __restrict__ scal) {
    int i = blockIdx.x * 256 + threadIdx.x;
    int lane = threadIdx.x & 63;
    float mx = unordf(((const u32*)scal)[0]);
    float e = __expf(att[i] - mx);
    #pragma unroll
    for (int off = 32; off > 0; off >>= 1) e += __shfl_down(e, off);
    if (lane == 0) atomicAdd(&scal[1], e);
}

__global__ void pooled_kernel(const u16* __restrict__ emb, const float* __restrict__ att,
                              const float* __restrict__ scal, float* __restrict__ pooled) {
    int tid = threadIdx.x;
    int n0 = blockIdx.x * 32;
    float mx = unordf(((const u32*)scal)[0]);
    float inv = 1.0f / scal[1];
    float a0 = 0.f, a1 = 0.f;
    for (int k = 0; k < 32; k++) {
        int n = n0 + k;
        float w = __expf(att[n] - mx) * inv;
        size_t b = (size_t)n * 512;
        a0 += w * bf2f(emb[b + tid]);
        a1 += w * bf2f(emb[b + tid + 256]);
    }
    atomicAdd(&pooled[tid], a0);
    atomicAdd(&pooled[tid + 256], a1);
}

__global__ void final_kernel(const float* __restrict__ pooled,
                             const float* __restrict__ g, const float* __restrict__ bln,
                             const float* __restrict__ fcw, const float* __restrict__ fcb,
                             float* __restrict__ out) {
    __shared__ float red[256];
    int tid = threadIdx.x;
    float x0 = pooled[tid], x1 = pooled[tid + 256];
    red[tid] = x0 + x1; __syncthreads();
    for (int s = 128; s > 0; s >>= 1) { if (tid < s) red[tid] += red[tid + s]; __syncthreads(); }
    float mu = red[0] * (1.0f / 512.0f); __syncthreads();
    float d0 = x0 - mu, d1 = x1 - mu;
    red[tid] = d0 * d0 + d1 * d1; __syncthreads();
    for (int s = 128; s > 0; s >>= 1) { if (tid < s) red[tid] += red[tid + s]; __syncthreads(); }
    float var = red[0] * (1.0f / 512.0f); __syncthreads();
    float rstd = rsqrtf(var + 1e-5f);
    float l0 = d0 * rstd * g[tid]       + bln[tid];
    float l1 = d1 * rstd * g[tid + 256] + bln[tid + 256];
    red[tid] = l0 * fcw[tid * 2] + l1 * fcw[(tid + 256) * 2]; __syncthreads();
    for (int s = 128; s > 0; s >>= 1) { if (tid < s) red[tid] += red[tid + s]; __syncthreads(); }
    float o0 = red[0] + fcb[0]; __syncthreads();
    red[tid] = l0 * fcw[tid * 2 + 1] + l1 * fcw[(tid + 256) * 2 + 1]; __syncthreads();
    for (int s = 128; s > 0; s >>= 1) { if (tid < s) red[tid] += red[tid + s]; __syncthreads(); }
    float o1 = red[0] + fcb[1];
    if (tid == 0) {
        float m = fmaxf(o0, o1);
        float e0 = expf(o0 - m), e1 = expf(o1 - m);
        float se = e0 + e1;
        out[0] = o0;
        out[1] = o1;
        out[2] = e0 / se;
        out[3] = e1 / se;
        out[4] = (o0 >= o1) ? 0.0f : 1.0f;
    }
}

// ---------------------------------------------------------------------------
extern "C" void kernel_launch(void* const* d_in, const int* in_sizes, int n_in,
                              void* d_out, int out_size, void* d_ws, size_t ws_size,
                              hipStream_t stream)
{
    const float* x      = (const float*)d_in[0];
    const float* fc1_w  = (const float*)d_in[1];
    const float* fc1_b  = (const float*)d_in[2];
    const float* wh_w   = (const float*)d_in[3];
    const float* wh_b   = (const float*)d_in[4];
    const float* wt_w   = (const float*)d_in[5];
    const float* wt_b   = (const float*)d_in[6];
    const float* lin1_w = (const float*)d_in[7];
    const float* lin1_b = (const float*)d_in[8];
    const float* lin2_w = (const float*)d_in[9];
    const float* lin2_b = (const float*)d_in[10];
    const float* att1_w = (const float*)d_in[11];
    const float* att1_b = (const float*)d_in[12];
    const float* att2_w = (const float*)d_in[13];
    const float* att2_b = (const float*)d_in[14];
    const float* ln_g   = (const float*)d_in[15];
    const float* ln_b   = (const float*)d_in[16];
    const float* fc_w   = (const float*)d_in[17];
    const float* fc_b   = (const float*)d_in[18];
    float* out = (float*)d_out;
    char* ws = (char*)d_ws;

    u16*   fc1T   = (u16*)(ws + 0);
    u16*   whT    = (u16*)(ws + 1048576);
    u16*   wtT    = (u16*)(ws + 1572864);
    u16*   l1T    = (u16*)(ws + 2097152);
    u16*   l2T    = (u16*)(ws + 2621440);
    u16*   a1T    = (u16*)(ws + 3145728);
    float* tv     = (float*)(ws + 3407872);
    int*   ti     = (int*)(ws + 3604480);
    float* att    = (float*)(ws + 3801088);
    float* colsum = (float*)(ws + 3833856);
    float* pooled = (float*)(ws + 3835904);
    float* scal   = (float*)(ws + 3837952);
    u32*   tvp    = (u32*)(ws + 4194304);
    u16*   hbf    = (u16*)(ws + 14680064);   // 8 MB  [h; later s1]
    u16*   ehbf   = (u16*)(ws + 23068672);   // 8 MB  [e_h; later a1 fp32]
    u16*   etbf   = (u16*)(ws + 31457280);   // 8 MB  [e_t; later emb]
    u16*   s2bf   = (u16*)(ws + 39845888);   // 8 MB  [s2]
    u16*   xbf    = (u16*)(ws + 23068672);   // 16 MB (x bf16; dead after fc1)
    float* a1f    = (float*)(ws + 23068672); // 8 MB fp32 (after e_h dead)

    transpose_cvt<<<5760, dim3(32, 8), 0, stream>>>(
        fc1_w, fc1T, wh_w, whT, wt_w, wtT, lin1_w, l1T, lin2_w, l2T, att1_w, a1T, x, xbf);
    hipMemsetAsync(colsum, 0, 4160, stream);   // colsum + pooled + scal

    gemm_gl<1, 0, 1024><<<dim3(4, 64), 256, 0, stream>>>(xbf, fc1T, fc1_b, nullptr, hbf, 512);
    colsum_kernel<<<256, 256, 0, stream>>>(hbf, colsum);
    meanmix_kernel<<<2048, 256, 0, stream>>>(hbf, colsum);

    ehet_gl<<<dim3(8, 64), 256, 0, stream>>>(hbf, whT, wtT, wh_b, wt_b, ehbf, etbf);

    logits_topk<<<dim3(32, 64), 256, 0, stream>>>(ehbf, etbf, tvp);
    topk_merge<<<128, 64, 0, stream>>>(tvp, tv, ti);

    neighbor_kernel<<<2048, 256, 0, stream>>>(ehbf, etbf, tv, ti, hbf, s2bf);

    lin12_gl<<<dim3(4, 64), 256, 0, stream>>>(hbf, l1T, lin1_b, s2bf, l2T, lin2_b, etbf);

    gemm_gl<2, 1, 512><<<dim3(2, 64), 256, 0, stream>>>(etbf, a1T, att1_b, a1f, nullptr, 256);
    att2_kernel<<<2048, 256, 0, stream>>>(a1f, att2_w, att2_b, att);
    att_max<<<32, 256, 0, stream>>>(att, (u32*)scal);
    att_sum<<<32, 256, 0, stream>>>(att, scal);
    pooled_kernel<<<256, 256, 0, stream>>>(etbf, att, scal, pooled);

    final_kernel<<<1, 256, 0, stream>>>(pooled, ln_g, ln_b, fc_w, fc_b, out);
}

// Round 10
// 419.306 us; speedup vs baseline: 1.0928x; 1.0356x over previous
//
#include <hip/hip_runtime.h>
#include <hip/hip_bf16.h>
#include <cstdint>
#include <math.h>

typedef unsigned short u16;
typedef unsigned int u32;
typedef __bf16 bh;
typedef bh bh8 __attribute__((ext_vector_type(8)));
typedef float f32x4 __attribute__((ext_vector_type(4)));

#define SCALE_F 0.04419417382415922f  // 512^-0.5

__device__ __forceinline__ float bf2f(u16 u) {
    union { float f; unsigned int i; } v; v.i = ((unsigned int)u) << 16; return v.f;
}
__device__ __forceinline__ u16 f2bf(float f) {
    __hip_bfloat16 h = __float2bfloat16(f);
    return __builtin_bit_cast(u16, h);
}
__device__ __forceinline__ bh8 ld8_f32(const float* p) {
    float4 f0 = *(const float4*)p;
    float4 f1 = *(const float4*)(p + 4);
    bh8 r;
    r[0] = (bh)f0.x; r[1] = (bh)f0.y; r[2] = (bh)f0.z; r[3] = (bh)f0.w;
    r[4] = (bh)f1.x; r[5] = (bh)f1.y; r[6] = (bh)f1.z; r[7] = (bh)f1.w;
    return r;
}

// ordered-uint transforms (monotone with float order)
__device__ __forceinline__ u32 ordf(float f) {
    u32 u = __float_as_uint(f);
    return u ^ ((u32)((int)u >> 31) | 0x80000000u);
}
__device__ __forceinline__ float unordf(u32 s) {
    u32 u = (s & 0x80000000u) ? (s ^ 0x80000000u) : ~s;
    return __uint_as_float(u);
}
// 24-bit ordered value | 8-bit inverted local col idx (tie -> smaller idx wins)
__device__ __forceinline__ u32 pack_vi(float v, int inv_idx) {
    return (ordf(v) & 0xFFFFFF00u) | (u32)inv_idx;
}
__device__ __forceinline__ float unpack_v(u32 p) {
    return unordf(p & 0xFFFFFF00u);
}

// direct global->LDS 16B per lane; lds base wave-uniform (dest = base + lane*16)
__device__ __forceinline__ void gl_lds16(const u16* g, u16* l) {
    __builtin_amdgcn_global_load_lds(
        (const __attribute__((address_space(1))) void*)g,
        (__attribute__((address_space(3))) void*)l, 16, 0, 0);
}

// ---------------------------------------------------------------------------
// 6 weight transposes (fp32 [R,C] -> bf16 [C,R]) + x fp32->bf16, one dispatch
__global__ void transpose_cvt(const float* s0, u16* d0, const float* s1, u16* d1,
                              const float* s2, u16* d2, const float* s3, u16* d3,
                              const float* s4, u16* d4, const float* s5, u16* d5,
                              const float* xs, u16* xd) {
    int b = blockIdx.x;
    if (b >= 1664) {  // cvt_x part: 4096 blocks, 8 elems/thread
        int t = threadIdx.y * 32 + threadIdx.x;
        size_t i = ((size_t)(b - 1664) * 256 + t) * 8;
        *(bh8*)(xd + i) = ld8_f32(xs + i);
        return;
    }
    __shared__ float tsh[32][33];
    const float* src; u16* dst; int R, C, tt;
    if      (b < 512)  { src = s0; dst = d0; R = 1024; C = 512; tt = b; }
    else if (b < 768)  { src = s1; dst = d1; R = 512;  C = 512; tt = b - 512; }
    else if (b < 1024) { src = s2; dst = d2; R = 512;  C = 512; tt = b - 768; }
    else if (b < 1280) { src = s3; dst = d3; R = 512;  C = 512; tt = b - 1024; }
    else if (b < 1536) { src = s4; dst = d4; R = 512;  C = 512; tt = b - 1280; }
    else               { src = s5; dst = d5; R = 512;  C = 256; tt = b - 1536; }
    int ntx = C >> 5;
    int bx = (tt % ntx) * 32, by = (tt / ntx) * 32;
    int x = threadIdx.x, y = threadIdx.y;
    for (int i = 0; i < 32; i += 8)
        tsh[y + i][x] = src[(size_t)(by + y + i) * C + bx + x];
    __syncthreads();
    for (int i = 0; i < 32; i += 8)
        dst[(size_t)(bx + y + i) * R + by + x] = f2bf(tsh[x][y + i]);
}

// ---------------------------------------------------------------------------
// Single-buffered direct-to-LDS K-loop with XOR k-block swizzle (conflict fix
// verified R8: SQ_LDS_BANK_CONFLICT 12.7M -> 4.3M). Staging lane tid loads
// global k-block g = (tid&3)^((tid>>3)&3); readers fetch slot quad^((lr>>1)&3).
// Alds/Blds are 128*32 u16 (8KB each) -> small LDS for high block residency.
template<int KT>
__device__ __forceinline__ void kloop_sb(const u16* __restrict__ Ag, const u16* __restrict__ Bg,
                                         u16* Alds, u16* Blds, f32x4 (&acc)[4][4]) {
    const int tid = threadIdx.x;
    const int wave = tid >> 6, lane = tid & 63;
    const int lr = lane & 15, quad = lane >> 4;
    const int wm = (wave & 1) * 64, wn = (wave >> 1) * 64;
    const int r = tid >> 2;
    const int g8 = (((tid & 3) ^ ((tid >> 3) & 3))) * 8;   // swizzled k-block
    const int kbr8 = (quad ^ ((lr >> 1) & 3)) * 8;         // reader slot
    const u16* ga0 = Ag + (size_t)r * KT + g8;
    const u16* ga1 = ga0 + (size_t)64 * KT;
    const u16* gb0 = Bg + (size_t)r * KT + g8;
    const u16* gb1 = gb0 + (size_t)64 * KT;
    u16* la = Alds + wave * 512;   // wave-uniform
    u16* lb = Blds + wave * 512;
    #pragma unroll
    for (int k0 = 0; k0 < KT; k0 += 32) {
        __syncthreads();                 // prior reads done before LDS overwrite
        gl_lds16(ga0 + k0, la);
        gl_lds16(ga1 + k0, la + 2048);   // rows 64..127
        gl_lds16(gb0 + k0, lb);
        gl_lds16(gb1 + k0, lb + 2048);
        __syncthreads();                 // drains vmcnt -> LDS writes visible
        bh8 af[4], bf_[4];
        #pragma unroll
        for (int i = 0; i < 4; i++) {
            af[i]  = *(const bh8*)&Alds[(wm + i * 16 + lr) * 32 + kbr8];
            bf_[i] = *(const bh8*)&Blds[(wn + i * 16 + lr) * 32 + kbr8];
        }
        #pragma unroll
        for (int mi = 0; mi < 4; mi++)
            #pragma unroll
            for (int ni = 0; ni < 4; ni++)
                acc[mi][ni] = __builtin_amdgcn_mfma_f32_16x16x32_bf16(
                    af[mi], bf_[ni], acc[mi][ni], 0, 0, 0);
    }
}

template<int ACT, int F32OUT>
__device__ __forceinline__ void epilogue(f32x4 (&acc)[4][4], const float* bias,
                                         float* Cf, u16* Cb, int N, int m0, int n0) {
    const int tid = threadIdx.x;
    const int wave = tid >> 6, lane = tid & 63;
    const int lr = lane & 15, quad = lane >> 4;
    const int wm = (wave & 1) * 64, wn = (wave >> 1) * 64;
    #pragma unroll
    for (int ni = 0; ni < 4; ni++) {
        int col = n0 + wn + ni * 16 + lr;
        float bs = bias[col];
        #pragma unroll
        for (int mi = 0; mi < 4; mi++) {
            #pragma unroll
            for (int i = 0; i < 4; i++) {
                int row = m0 + wm + mi * 16 + quad * 4 + i;
                float v = acc[mi][ni][i] + bs;
                if (ACT == 1) v = fmaxf(v, 0.0f);
                if (ACT == 2) v = (v > 0.0f) ? v : 0.01f * v;
                size_t o = (size_t)row * N + col;
                if (F32OUT) Cf[o] = v;
                else        Cb[o] = f2bf(v);
            }
        }
    }
}

// NOTE (R9 lesson): __launch_bounds__(256,N) min-waves hints drove the
// allocator to 84 VGPR and massive scratch spill (FETCH 37->195MB). Plain
// (256) gives natural ~150 VGPR (R8) -> 3 waves/SIMD, no spill.
template<int ACT, int F32OUT, int KT>
__global__ __launch_bounds__(256) void gemm_gl(
    const u16* __restrict__ A, const u16* __restrict__ B, const float* __restrict__ bias,
    float* __restrict__ Cf, u16* __restrict__ Cb, int N)
{
    __shared__ __align__(16) u16 Alds[128 * 32];
    __shared__ __align__(16) u16 Blds[128 * 32];
    const int m0 = blockIdx.y * 128, n0 = blockIdx.x * 128;
    f32x4 acc[4][4] = {};
    kloop_sb<KT>(A + (size_t)m0 * KT, B + (size_t)n0 * KT, Alds, Blds, acc);
    epilogue<ACT, F32OUT>(acc, bias, Cf, Cb, N, m0, n0);
}

// fused e_h / e_t
__global__ __launch_bounds__(256) void ehet_gl(
    const u16* __restrict__ A, const u16* __restrict__ Bh, const u16* __restrict__ Bt,
    const float* __restrict__ bh_, const float* __restrict__ bt_,
    u16* __restrict__ Oh, u16* __restrict__ Ot)
{
    __shared__ __align__(16) u16 Alds[128 * 32];
    __shared__ __align__(16) u16 Blds[128 * 32];
    const int bx = blockIdx.x;
    const int m0 = blockIdx.y * 128, n0 = (bx & 3) * 128;
    const u16* B = (bx < 4) ? Bh : Bt;
    const float* bias = (bx < 4) ? bh_ : bt_;
    u16* O = (bx < 4) ? Oh : Ot;
    f32x4 acc[4][4] = {};
    kloop_sb<512>(A + (size_t)m0 * 512, B + (size_t)n0 * 512, Alds, Blds, acc);
    epilogue<0, 0>(acc, bias, nullptr, O, 512, m0, n0);
}

// fused emb = lrelu(s1@l1+b1) + lrelu(s2@l2+b2)
__global__ __launch_bounds__(256) void lin12_gl(
    const u16* __restrict__ A1, const u16* __restrict__ B1, const float* __restrict__ b1,
    const u16* __restrict__ A2, const u16* __restrict__ B2, const float* __restrict__ b2,
    u16* __restrict__ O)
{
    __shared__ __align__(16) u16 Alds[128 * 32];
    __shared__ __align__(16) u16 Blds[128 * 32];
    const int m0 = blockIdx.y * 128, n0 = blockIdx.x * 128;
    f32x4 acc1[4][4] = {}, acc2[4][4] = {};
    kloop_sb<512>(A1 + (size_t)m0 * 512, B1 + (size_t)n0 * 512, Alds, Blds, acc1);
    kloop_sb<512>(A2 + (size_t)m0 * 512, B2 + (size_t)n0 * 512, Alds, Blds, acc2);
    const int tid = threadIdx.x;
    const int wave = tid >> 6, lane = tid & 63;
    const int lr = lane & 15, quad = lane >> 4;
    const int wm = (wave & 1) * 64, wn = (wave >> 1) * 64;
    #pragma unroll
    for (int ni = 0; ni < 4; ni++) {
        int col = n0 + wn + ni * 16 + lr;
        float bs1 = b1[col], bs2 = b2[col];
        #pragma unroll
        for (int mi = 0; mi < 4; mi++) {
            #pragma unroll
            for (int i = 0; i < 4; i++) {
                int row = m0 + wm + mi * 16 + quad * 4 + i;
                float v1 = acc1[mi][ni][i] + bs1;
                v1 = (v1 > 0.0f) ? v1 : 0.01f * v1;
                float v2 = acc2[mi][ni][i] + bs2;
                v2 = (v2 > 0.0f) ? v2 : 0.01f * v2;
                O[(size_t)row * 512 + col] = f2bf(v1 + v2);
            }
        }
    }
}

// ---------------------------------------------------------------------------
// fused logits GEMM + branchless packed top-6 over a 256-col span. Grid (32,64).
// LDS = 8K + 8K + 33.3K = 49.7KB -> 3 blocks/CU at natural VGPR (<=170).
__global__ __launch_bounds__(256) void logits_topk(
    const u16* __restrict__ Ah, const u16* __restrict__ Bt, u32* __restrict__ tvp)
{
    __shared__ __align__(16) u16 Alds[128 * 32];
    __shared__ __align__(16) u16 Blds[128 * 32];
    __shared__ u32 S[128 * 65];
    const int tid = threadIdx.x;
    const int m0 = blockIdx.y * 128;
    const int cb0 = blockIdx.x * 256;
    const int lane = tid & 63, wave = tid >> 6;
    const int wm = (wave & 1) * 64, wn = (wave >> 1) * 64;
    const int lr = lane & 15, quad = lane >> 4;
    const int srow = tid >> 1, scg = tid & 1;

    u32 v0 = 0, v1 = 0, v2 = 0, v3 = 0, v4 = 0, v5 = 0;

    for (int nt = 0; nt < 2; nt++) {
        f32x4 acc[4][4] = {};
        kloop_sb<512>(Ah + (size_t)m0 * 512,
                      Bt + (size_t)(cb0 + nt * 128) * 512, Alds, Blds, acc);
        #pragma unroll
        for (int half = 0; half < 2; half++) {
            __syncthreads();
            if ((wave >> 1) == half) {
                #pragma unroll
                for (int mi = 0; mi < 4; mi++)
                    #pragma unroll
                    for (int ni = 0; ni < 4; ni++)
                        #pragma unroll
                        for (int i = 0; i < 4; i++) {
                            int colLocal = nt * 128 + half * 64 + ni * 16 + lr;
                            S[(wm + mi * 16 + quad * 4 + i) * 65 + ni * 16 + lr]
                                = pack_vi(acc[mi][ni][i], 255 - colLocal);
                        }
            }
            __syncthreads();
            const u32* Sr = &S[srow * 65 + scg * 32];
            #pragma unroll 8
            for (int c = 0; c < 32; c++) {
                u32 x = Sr[c];
                v5 = max(v5, min(v4, x));
                v4 = max(v4, min(v3, x));
                v3 = max(v3, min(v2, x));
                v2 = max(v2, min(v1, x));
                v1 = max(v1, min(v0, x));
                v0 = max(v0, x);
            }
        }
    }
    __syncthreads();
    {
        u32* dst = &S[srow * 65 + scg * 6];
        dst[0] = v0; dst[1] = v1; dst[2] = v2; dst[3] = v3; dst[4] = v4; dst[5] = v5;
    }
    __syncthreads();
    if (tid < 128) {
        u32 m0v = 0, m1v = 0, m2v = 0, m3v = 0, m4v = 0, m5v = 0;
        const u32* Sr = &S[tid * 65];
        #pragma unroll
        for (int s = 0; s < 12; s++) {
            u32 x = Sr[s];
            m5v = max(m5v, min(m4v, x));
            m4v = max(m4v, min(m3v, x));
            m3v = max(m3v, min(m2v, x));
            m2v = max(m2v, min(m1v, x));
            m1v = max(m1v, min(m0v, x));
            m0v = max(m0v, x);
        }
        u32* dst = tvp + (size_t)(m0 + tid) * 192 + blockIdx.x * 6;
        dst[0] = m0v; dst[1] = m1v; dst[2] = m2v;
        dst[3] = m3v; dst[4] = m4v; dst[5] = m5v;
    }
}

// merge 32 packed partial top-6 lists per row -> final top-6 (fp32 val + idx)
__global__ void topk_merge(const u32* __restrict__ tvp,
                           float* __restrict__ tv, int* __restrict__ ti)
{
    int r = blockIdx.x * 64 + threadIdx.x;
    u32 v[6]; int ix[6];
    #pragma unroll
    for (int j = 0; j < 6; j++) { v[j] = 0; ix[j] = 0; }
    const u32* pv = tvp + (size_t)r * 192;
    for (int b = 0; b < 32; b++) {
        #pragma unroll
        for (int j2 = 0; j2 < 6; j2++) {
            u32 p = pv[b * 6 + j2];
            if (p <= v[5]) break;     // group is descending: rest can't insert
            v[5] = p; ix[5] = b * 256 + 255 - (int)(p & 255u);
            #pragma unroll
            for (int j = 5; j > 0; j--) {
                if (v[j] > v[j - 1]) {
                    u32 tf = v[j]; v[j] = v[j - 1]; v[j - 1] = tf;
                    int tx = ix[j]; ix[j] = ix[j - 1]; ix[j - 1] = tx;
                }
            }
        }
    }
    #pragma unroll
    for (int j = 0; j < 6; j++) {
        tv[(size_t)r * 6 + j] = unpack_v(v[j]) * SCALE_F;
        ti[(size_t)r * 6 + j] = ix[j];
    }
}

// ---------------------------------------------------------------------------
// neighbor aggregation, one WAVE per row (no block barriers). fp32 math.
__global__ __launch_bounds__(256) void neighbor_kernel(
    const u16* __restrict__ eH, const u16* __restrict__ eT,
    const float* __restrict__ tv, const int* __restrict__ ti,
    u16* __restrict__ s1, u16* __restrict__ s2)
{
    const int tid = threadIdx.x, wave = tid >> 6, lane = tid & 63;
    const int n = blockIdx.x * 4 + wave;
    float tw[6]; int id[6];
    #pragma unroll
    for (int j = 0; j < 6; j++) {
        tw[j] = tv[n * 6 + j];
        int t = ti[n * 6 + j];
        id[j] = ((unsigned)t < 8192u) ? t : 0;
    }
    float mx = tw[0];
    #pragma unroll
    for (int j = 1; j < 6; j++) mx = fmaxf(mx, tw[j]);
    float p[6]; float ps = 0.f;
    #pragma unroll
    for (int j = 0; j < 6; j++) { p[j] = __expf(tw[j] - mx); ps += p[j]; }
    float inv = 1.0f / ps;
    #pragma unroll
    for (int j = 0; j < 6; j++) p[j] *= inv;

    const size_t base = (size_t)n * 512 + lane * 8;
    float eh[8];
    { bh8 v = *(const bh8*)(eH + base);
      #pragma unroll
      for (int c = 0; c < 8; c++) eh[c] = (float)v[c]; }
    float nb[6][8];
    #pragma unroll
    for (int j = 0; j < 6; j++) {
        bh8 v = *(const bh8*)(eT + (size_t)id[j] * 512 + lane * 8);
        #pragma unroll
        for (int c = 0; c < 8; c++) nb[j][c] = (float)v[c];
    }
    float ka[6];
    #pragma unroll
    for (int j = 0; j < 6; j++) {
        float s = 0.f;
        #pragma unroll
        for (int c = 0; c < 8; c++) {
            float e = p[j] * nb[j][c] + (1.f - p[j]) * eh[c];
            float x = eh[c] + e;
            x = fminf(fmaxf(x, -15.f), 15.f);
            float ex = __expf(2.f * x);
            float g = 1.f - 2.f / (ex + 1.f);   // tanh
            s += nb[j][c] * g;
        }
        #pragma unroll
        for (int off = 32; off > 0; off >>= 1) s += __shfl_down(s, off);
        ka[j] = __shfl(s, 0);
    }
    float m2 = ka[0];
    #pragma unroll
    for (int j = 1; j < 6; j++) m2 = fmaxf(m2, ka[j]);
    float kp[6]; float ks = 0.f;
    #pragma unroll
    for (int j = 0; j < 6; j++) { kp[j] = __expf(ka[j] - m2); ks += kp[j]; }
    float inv2 = 1.0f / ks;
    #pragma unroll
    for (int j = 0; j < 6; j++) kp[j] *= inv2;
    bh8 o1, o2;
    #pragma unroll
    for (int c = 0; c < 8; c++) {
        float eN = 0.f;
        #pragma unroll
        for (int j = 0; j < 6; j++) eN += kp[j] * nb[j][c];
        o1[c] = (bh)(eh[c] + eN);
        o2[c] = (bh)(eh[c] * eN);
    }
    *(bh8*)(s1 + base) = o1;
    *(bh8*)(s2 + base) = o2;
}

// ---------------------------------------------------------------------------
__global__ void colsum_kernel(const u16* __restrict__ h, float* __restrict__ colsum) {
    int tid = threadIdx.x;
    int n0 = blockIdx.x * 32;
    float a0 = 0.f, a1 = 0.f;
    for (int k = 0; k < 32; k++) {
        size_t b = (size_t)(n0 + k) * 512;
        a0 += bf2f(h[b + tid]); a1 += bf2f(h[b + tid + 256]);
    }
    atomicAdd(&colsum[tid], a0);
    atomicAdd(&colsum[tid + 256], a1);
}

__global__ void meanmix_kernel(u16* __restrict__ h, const float* __restrict__ colsum) {
    size_t i = ((size_t)blockIdx.x * 256 + threadIdx.x) * 8;
    int col = (int)(i & 511);
    union { int4 v; u16 s[8]; } u;
    u.v = *(const int4*)&h[i];
    #pragma unroll
    for (int j = 0; j < 8; j++)
        u.s[j] = f2bf((bf2f(u.s[j]) + colsum[col + j] * (1.0f / 8192.0f)) * 0.5f);
    *(int4*)&h[i] = u.v;
}

__global__ __launch_bounds__(256) void att2_kernel(
    const float* __restrict__ a1, const float* __restrict__ w,
    const float* __restrict__ b, float* __restrict__ att)
{
    int row = blockIdx.x * 4 + (threadIdx.x >> 6);
    int lane = threadIdx.x & 63;
    const float* pr = a1 + (size_t)row * 256;
    float s = 0.f;
    #pragma unroll
    for (int k = 0; k < 4; k++) { int c = lane + k * 64; s += pr[c] * w[c]; }
    #pragma unroll
    for (int off = 32; off > 0; off >>= 1) s += __shfl_down(s, off);
    if (lane == 0) att[row] = s + b[0];
}

// parallel softmax stats: ordered-u32 atomicMax, then atomicAdd of exp sums
__global__ void att_max(const float* __restrict__ att, u32* __restrict__ scal_u) {
    int i = blockIdx.x * 256 + threadIdx.x;
    int lane = threadIdx.x & 63;
    u32 o = ordf(att[i]);
    #pragma unroll
    for (int off = 32; off > 0; off >>= 1) o = max(o, (u32)__shfl_down((int)o, off));
    if (lane == 0) atomicMax(&scal_u[0], o);
}
__global__ void att_sum(const float* __restrict__ att, float* __restrict__ scal) {
    int i = blockIdx.x * 256 + threadIdx.x;
    int lane = threadIdx.x & 63;
    float mx = unordf(((const u32*)scal)[0]);
    float e = __expf(att[i] - mx);
    #pragma unroll
    for (int off = 32; off > 0; off >>= 1) e += __shfl_down(e, off);
    if (lane == 0) atomicAdd(&scal[1], e);
}

__global__ void pooled_kernel(const u16* __restrict__ emb, const float* __restrict__ att,
                              const float* __restrict__ scal, float* __restrict__ pooled) {
    int tid = threadIdx.x;
    int n0 = blockIdx.x * 32;
    float mx = unordf(((const u32*)scal)[0]);
    float inv = 1.0f / scal[1];
    float a0 = 0.f, a1 = 0.f;
    for (int k = 0; k < 32; k++) {
        int n = n0 + k;
        float w = __expf(att[n] - mx) * inv;
        size_t b = (size_t)n * 512;
        a0 += w * bf2f(emb[b + tid]);
        a1 += w * bf2f(emb[b + tid + 256]);
    }
    atomicAdd(&pooled[tid], a0);
    atomicAdd(&pooled[tid + 256], a1);
}

__global__ void final_kernel(const float* __restrict__ pooled,
                             const float* __restrict__ g, const float* __restrict__ bln,
                             const float* __restrict__ fcw, const float* __restrict__ fcb,
                             float* __restrict__ out) {
    __shared__ float red[256];
    int tid = threadIdx.x;
    float x0 = pooled[tid], x1 = pooled[tid + 256];
    red[tid] = x0 + x1; __syncthreads();
    for (int s = 128; s > 0; s >>= 1) { if (tid < s) red[tid] += red[tid + s]; __syncthreads(); }
    float mu = red[0] * (1.0f / 512.0f); __syncthreads();
    float d0 = x0 - mu, d1 = x1 - mu;
    red[tid] = d0 * d0 + d1 * d1; __syncthreads();
    for (int s = 128; s > 0; s >>= 1) { if (tid < s) red[tid] += red[tid + s]; __syncthreads(); }
    float var = red[0] * (1.0f / 512.0f); __syncthreads();
    float rstd = rsqrtf(var + 1e-5f);
    float l0 = d0 * rstd * g[tid]       + bln[tid];
    float l1 = d1 * rstd * g[tid + 256] + bln[tid + 256];
    red[tid] = l0 * fcw[tid * 2] + l1 * fcw[(tid + 256) * 2]; __syncthreads();
    for (int s = 128; s > 0; s >>= 1) { if (tid < s) red[tid] += red[tid + s]; __syncthreads(); }
    float o0 = red[0] + fcb[0]; __syncthreads();
    red[tid] = l0 * fcw[tid * 2 + 1] + l1 * fcw[(tid + 256) * 2 + 1]; __syncthreads();
    for (int s = 128; s > 0; s >>= 1) { if (tid < s) red[tid] += red[tid + s]; __syncthreads(); }
    float o1 = red[0] + fcb[1];
    if (tid == 0) {
        float m = fmaxf(o0, o1);
        float e0 = expf(o0 - m), e1 = expf(o1 - m);
        float se = e0 + e1;
        out[0] = o0;
        out[1] = o1;
        out[2] = e0 / se;
        out[3] = e1 / se;
        out[4] = (o0 >= o1) ? 0.0f : 1.0f;
    }
}

// ---------------------------------------------------------------------------
extern "C" void kernel_launch(void* const* d_in, const int* in_sizes, int n_in,
                              void* d_out, int out_size, void* d_ws, size_t ws_size,
                              hipStream_t stream)
{
    const float* x      = (const float*)d_in[0];
    const float* fc1_w  = (const float*)d_in[1];
    const float* fc1_b  = (const float*)d_in[2];
    const float* wh_w   = (const float*)d_in[3];
    const float* wh_b   = (const float*)d_in[4];
    const float* wt_w   = (const float*)d_in[5];
    const float* wt_b   = (const float*)d_in[6];
    const float* lin1_w = (const float*)d_in[7];
    const float* lin1_b = (const float*)d_in[8];
    const float* lin2_w = (const float*)d_in[9];
    const float* lin2_b = (const float*)d_in[10];
    const float* att1_w = (const float*)d_in[11];
    const float* att1_b = (const float*)d_in[12];
    const float* att2_w = (const float*)d_in[13];
    const float* att2_b = (const float*)d_in[14];
    const float* ln_g   = (const float*)d_in[15];
    const float* ln_b   = (const float*)d_in[16];
    const float* fc_w   = (const float*)d_in[17];
    const float* fc_b   = (const float*)d_in[18];
    float* out = (float*)d_out;
    char* ws = (char*)d_ws;

    u16*   fc1T   = (u16*)(ws + 0);
    u16*   whT    = (u16*)(ws + 1048576);
    u16*   wtT    = (u16*)(ws + 1572864);
    u16*   l1T    = (u16*)(ws + 2097152);
    u16*   l2T    = (u16*)(ws + 2621440);
    u16*   a1T    = (u16*)(ws + 3145728);
    float* tv     = (float*)(ws + 3407872);
    int*   ti     = (int*)(ws + 3604480);
    float* att    = (float*)(ws + 3801088);
    float* colsum = (float*)(ws + 3833856);
    float* pooled = (float*)(ws + 3835904);
    float* scal   = (float*)(ws + 3837952);
    u32*   tvp    = (u32*)(ws + 4194304);
    u16*   hbf    = (u16*)(ws + 14680064);   // 8 MB  [h; later s1]
    u16*   ehbf   = (u16*)(ws + 23068672);   // 8 MB  [e_h; later a1 fp32]
    u16*   etbf   = (u16*)(ws + 31457280);   // 8 MB  [e_t; later emb]
    u16*   s2bf   = (u16*)(ws + 39845888);   // 8 MB  [s2]
    u16*   xbf    = (u16*)(ws + 23068672);   // 16 MB (x bf16; dead after fc1)
    float* a1f    = (float*)(ws + 23068672); // 8 MB fp32 (after e_h dead)

    transpose_cvt<<<5760, dim3(32, 8), 0, stream>>>(
        fc1_w, fc1T, wh_w, whT, wt_w, wtT, lin1_w, l1T, lin2_w, l2T, att1_w, a1T, x, xbf);
    hipMemsetAsync(colsum, 0, 4160, stream);   // colsum + pooled + scal

    gemm_gl<1, 0, 1024><<<dim3(4, 64), 256, 0, stream>>>(xbf, fc1T, fc1_b, nullptr, hbf, 512);
    colsum_kernel<<<256, 256, 0, stream>>>(hbf, colsum);
    meanmix_kernel<<<2048, 256, 0, stream>>>(hbf, colsum);

    ehet_gl<<<dim3(8, 64), 256, 0, stream>>>(hbf, whT, wtT, wh_b, wt_b, ehbf, etbf);

    logits_topk<<<dim3(32, 64), 256, 0, stream>>>(ehbf, etbf, tvp);
    topk_merge<<<128, 64, 0, stream>>>(tvp, tv, ti);

    neighbor_kernel<<<2048, 256, 0, stream>>>(ehbf, etbf, tv, ti, hbf, s2bf);

    lin12_gl<<<dim3(4, 64), 256, 0, stream>>>(hbf, l1T, lin1_b, s2bf, l2T, lin2_b, etbf);

    gemm_gl<2, 1, 512><<<dim3(2, 64), 256, 0, stream>>>(etbf, a1T, att1_b, a1f, nullptr, 256);
    att2_kernel<<<2048, 256, 0, stream>>>(a1f, att2_w, att2_b, att);
    att_max<<<32, 256, 0, stream>>>(att, (u32*)scal);
    att_sum<<<32, 256, 0, stream>>>(att, scal);
    pooled_kernel<<<256, 256, 0, stream>>>(etbf, att, scal, pooled);

    final_kernel<<<1, 256, 0, stream>>>(pooled, ln_g, ln_b, fc_w, fc_b, out);
}

// Round 11
// 381.175 us; speedup vs baseline: 1.2021x; 1.1000x over previous
//
#include <hip/hip_runtime.h>
#include <hip/hip_bf16.h>
#include <cstdint>
#include <math.h>

typedef unsigned short u16;
typedef unsigned int u32;
typedef __bf16 bh;
typedef bh bh8 __attribute__((ext_vector_type(8)));
typedef float f32x4 __attribute__((ext_vector_type(4)));

#define SCALE_F 0.04419417382415922f  // 512^-0.5

__device__ __forceinline__ float bf2f(u16 u) {
    union { float f; unsigned int i; } v; v.i = ((unsigned int)u) << 16; return v.f;
}
__device__ __forceinline__ u16 f2bf(float f) {
    __hip_bfloat16 h = __float2bfloat16(f);
    return __builtin_bit_cast(u16, h);
}
__device__ __forceinline__ bh8 ld8_f32(const float* p) {
    float4 f0 = *(const float4*)p;
    float4 f1 = *(const float4*)(p + 4);
    bh8 r;
    r[0] = (bh)f0.x; r[1] = (bh)f0.y; r[2] = (bh)f0.z; r[3] = (bh)f0.w;
    r[4] = (bh)f1.x; r[5] = (bh)f1.y; r[6] = (bh)f1.z; r[7] = (bh)f1.w;
    return r;
}

// ordered-uint transforms (monotone with float order)
__device__ __forceinline__ u32 ordf(float f) {
    u32 u = __float_as_uint(f);
    return u ^ ((u32)((int)u >> 31) | 0x80000000u);
}
__device__ __forceinline__ float unordf(u32 s) {
    u32 u = (s & 0x80000000u) ? (s ^ 0x80000000u) : ~s;
    return __uint_as_float(u);
}
// 24-bit ordered value | 8-bit inverted local col idx (tie -> smaller idx wins)
__device__ __forceinline__ u32 pack_vi(float v, int inv_idx) {
    return (ordf(v) & 0xFFFFFF00u) | (u32)inv_idx;
}
__device__ __forceinline__ float unpack_v(u32 p) {
    return unordf(p & 0xFFFFFF00u);
}

// direct global->LDS 16B per lane; lds base wave-uniform (dest = base + lane*16)
__device__ __forceinline__ void gl_lds16(const u16* g, u16* l) {
    __builtin_amdgcn_global_load_lds(
        (const __attribute__((address_space(1))) void*)g,
        (__attribute__((address_space(3))) void*)l, 16, 0, 0);
}

// ---------------------------------------------------------------------------
// 6 weight transposes (fp32 [R,C] -> bf16 [C,R]) + x fp32->bf16, one dispatch
__global__ void transpose_cvt(const float* s0, u16* d0, const float* s1, u16* d1,
                              const float* s2, u16* d2, const float* s3, u16* d3,
                              const float* s4, u16* d4, const float* s5, u16* d5,
                              const float* xs, u16* xd) {
    int b = blockIdx.x;
    if (b >= 1664) {  // cvt_x part: 4096 blocks, 8 elems/thread
        int t = threadIdx.y * 32 + threadIdx.x;
        size_t i = ((size_t)(b - 1664) * 256 + t) * 8;
        *(bh8*)(xd + i) = ld8_f32(xs + i);
        return;
    }
    __shared__ float tsh[32][33];
    const float* src; u16* dst; int R, C, tt;
    if      (b < 512)  { src = s0; dst = d0; R = 1024; C = 512; tt = b; }
    else if (b < 768)  { src = s1; dst = d1; R = 512;  C = 512; tt = b - 512; }
    else if (b < 1024) { src = s2; dst = d2; R = 512;  C = 512; tt = b - 768; }
    else if (b < 1280) { src = s3; dst = d3; R = 512;  C = 512; tt = b - 1024; }
    else if (b < 1536) { src = s4; dst = d4; R = 512;  C = 512; tt = b - 1280; }
    else               { src = s5; dst = d5; R = 512;  C = 256; tt = b - 1536; }
    int ntx = C >> 5;
    int bx = (tt % ntx) * 32, by = (tt / ntx) * 32;
    int x = threadIdx.x, y = threadIdx.y;
    for (int i = 0; i < 32; i += 8)
        tsh[y + i][x] = src[(size_t)(by + y + i) * C + bx + x];
    __syncthreads();
    for (int i = 0; i < 32; i += 8)
        dst[(size_t)(bx + y + i) * R + by + x] = f2bf(tsh[x][y + i]);
}

// ---------------------------------------------------------------------------
// 64-row K-loop, direct-to-LDS with XOR k-block swizzle (R8-verified: 3x fewer
// LDS bank conflicts). A-tile 64xBK; B-tile (NF*32)xBK (NF=2 -> 64, NF=4 -> 128).
// Wave tile = 32 x NF*16. Small tiles -> low VGPR (acc[2][NF]) + small LDS ->
// 4+ blocks/CU residency (the R10 lesson: 2 blocks/CU can't hide the
// per-iter load->barrier drain).
template<int KT, int NF>
__device__ __forceinline__ void kloop64(const u16* __restrict__ Ag, const u16* __restrict__ Bg,
                                        u16* Alds, u16* Blds, f32x4 (&acc)[2][NF]) {
    const int tid = threadIdx.x;
    const int wave = tid >> 6, lane = tid & 63;
    const int lr = lane & 15, quad = lane >> 4;
    const int wm = (wave & 1) * 32, wn = (wave >> 1) * (NF * 16);
    const int r = tid >> 2;
    const int g8 = (((tid & 3) ^ ((tid >> 3) & 3))) * 8;   // swizzled k-block
    const int kbr8 = (quad ^ ((lr >> 1) & 3)) * 8;         // reader slot
    const u16* ga  = Ag + (size_t)r * KT + g8;
    const u16* gb0 = Bg + (size_t)r * KT + g8;
    const u16* gb1 = gb0 + (size_t)64 * KT;                // B rows 64..127 (NF=4)
    u16* la = Alds + wave * 512;   // wave-uniform
    u16* lb = Blds + wave * 512;
    #pragma unroll
    for (int k0 = 0; k0 < KT; k0 += 32) {
        __syncthreads();                 // prior reads done before LDS overwrite
        gl_lds16(ga + k0, la);
        gl_lds16(gb0 + k0, lb);
        if (NF == 4) gl_lds16(gb1 + k0, lb + 2048);
        __syncthreads();                 // drains vmcnt -> LDS writes visible
        bh8 af[2], bf_[NF];
        #pragma unroll
        for (int i = 0; i < 2; i++)
            af[i] = *(const bh8*)&Alds[(wm + i * 16 + lr) * 32 + kbr8];
        #pragma unroll
        for (int i = 0; i < NF; i++)
            bf_[i] = *(const bh8*)&Blds[(wn + i * 16 + lr) * 32 + kbr8];
        #pragma unroll
        for (int mi = 0; mi < 2; mi++)
            #pragma unroll
            for (int ni = 0; ni < NF; ni++)
                acc[mi][ni] = __builtin_amdgcn_mfma_f32_16x16x32_bf16(
                    af[mi], bf_[ni], acc[mi][ni], 0, 0, 0);
    }
}

template<int ACT, int F32OUT>
__device__ __forceinline__ void epilogue64(f32x4 (&acc)[2][2], const float* bias,
                                           float* Cf, u16* Cb, int N, int m0, int n0) {
    const int tid = threadIdx.x;
    const int wave = tid >> 6, lane = tid & 63;
    const int lr = lane & 15, quad = lane >> 4;
    const int wm = (wave & 1) * 32, wn = (wave >> 1) * 32;
    #pragma unroll
    for (int ni = 0; ni < 2; ni++) {
        int col = n0 + wn + ni * 16 + lr;
        float bs = bias[col];
        #pragma unroll
        for (int mi = 0; mi < 2; mi++) {
            #pragma unroll
            for (int i = 0; i < 4; i++) {
                int row = m0 + wm + mi * 16 + quad * 4 + i;
                float v = acc[mi][ni][i] + bs;
                if (ACT == 1) v = fmaxf(v, 0.0f);
                if (ACT == 2) v = (v > 0.0f) ? v : 0.01f * v;
                size_t o = (size_t)row * N + col;
                if (F32OUT) Cf[o] = v;
                else        Cb[o] = f2bf(v);
            }
        }
    }
}

// 64x64-tile GEMM: out = act(A @ B^T + bias). grid (N/64, M/64).
template<int ACT, int F32OUT, int KT>
__global__ __launch_bounds__(256) void gemm64(
    const u16* __restrict__ A, const u16* __restrict__ B, const float* __restrict__ bias,
    float* __restrict__ Cf, u16* __restrict__ Cb, int N)
{
    __shared__ __align__(16) u16 Alds[64 * 32];
    __shared__ __align__(16) u16 Blds[64 * 32];
    const int m0 = blockIdx.y * 64, n0 = blockIdx.x * 64;
    f32x4 acc[2][2] = {};
    kloop64<KT, 2>(A + (size_t)m0 * KT, B + (size_t)n0 * KT, Alds, Blds, acc);
    epilogue64<ACT, F32OUT>(acc, bias, Cf, Cb, N, m0, n0);
}

// fused e_h / e_t: grid (16, 128); bx<8 -> wh, else wt
__global__ __launch_bounds__(256) void ehet64(
    const u16* __restrict__ A, const u16* __restrict__ Bh, const u16* __restrict__ Bt,
    const float* __restrict__ bh_, const float* __restrict__ bt_,
    u16* __restrict__ Oh, u16* __restrict__ Ot)
{
    __shared__ __align__(16) u16 Alds[64 * 32];
    __shared__ __align__(16) u16 Blds[64 * 32];
    const int bx = blockIdx.x;
    const int m0 = blockIdx.y * 64, n0 = (bx & 7) * 64;
    const u16* B = (bx < 8) ? Bh : Bt;
    const float* bias = (bx < 8) ? bh_ : bt_;
    u16* O = (bx < 8) ? Oh : Ot;
    f32x4 acc[2][2] = {};
    kloop64<512, 2>(A + (size_t)m0 * 512, B + (size_t)n0 * 512, Alds, Blds, acc);
    epilogue64<0, 0>(acc, bias, nullptr, O, 512, m0, n0);
}

// fused emb = lrelu(s1@l1+b1) + lrelu(s2@l2+b2), grid (8, 128)
__global__ __launch_bounds__(256) void lin12_64(
    const u16* __restrict__ A1, const u16* __restrict__ B1, const float* __restrict__ b1,
    const u16* __restrict__ A2, const u16* __restrict__ B2, const float* __restrict__ b2,
    u16* __restrict__ O)
{
    __shared__ __align__(16) u16 Alds[64 * 32];
    __shared__ __align__(16) u16 Blds[64 * 32];
    const int m0 = blockIdx.y * 64, n0 = blockIdx.x * 64;
    f32x4 acc1[2][2] = {}, acc2[2][2] = {};
    kloop64<512, 2>(A1 + (size_t)m0 * 512, B1 + (size_t)n0 * 512, Alds, Blds, acc1);
    kloop64<512, 2>(A2 + (size_t)m0 * 512, B2 + (size_t)n0 * 512, Alds, Blds, acc2);
    const int tid = threadIdx.x;
    const int wave = tid >> 6, lane = tid & 63;
    const int lr = lane & 15, quad = lane >> 4;
    const int wm = (wave & 1) * 32, wn = (wave >> 1) * 32;
    #pragma unroll
    for (int ni = 0; ni < 2; ni++) {
        int col = n0 + wn + ni * 16 + lr;
        float bs1 = b1[col], bs2 = b2[col];
        #pragma unroll
        for (int mi = 0; mi < 2; mi++) {
            #pragma unroll
            for (int i = 0; i < 4; i++) {
                int row = m0 + wm + mi * 16 + quad * 4 + i;
                float v1 = acc1[mi][ni][i] + bs1;
                v1 = (v1 > 0.0f) ? v1 : 0.01f * v1;
                float v2 = acc2[mi][ni][i] + bs2;
                v2 = (v2 > 0.0f) ? v2 : 0.01f * v2;
                O[(size_t)row * 512 + col] = f2bf(v1 + v2);
            }
        }
    }
}

// ---------------------------------------------------------------------------
// fused logits GEMM + branchless packed top-6. Block = 64 rows x 256 cols,
// grid (32, 128) = 4096 blocks. Wave tile 32x64 (acc[2][4] = 32 VGPR).
// LDS = 4K(A) + 8K(B) + 16.6K(S) = 28.6KB -> 4-5 blocks/CU.
__global__ __launch_bounds__(256) void logits_topk(
    const u16* __restrict__ Ah, const u16* __restrict__ Bt, u32* __restrict__ tvp)
{
    __shared__ __align__(16) u16 Alds[64 * 32];
    __shared__ __align__(16) u16 Blds[128 * 32];
    __shared__ u32 S[64 * 65];
    const int tid = threadIdx.x;
    const int m0 = blockIdx.y * 64;
    const int cb0 = blockIdx.x * 256;
    const int lane = tid & 63, wave = tid >> 6;
    const int wm = (wave & 1) * 32, wn = (wave >> 1) * 64;
    const int lr = lane & 15, quad = lane >> 4;
    const int srow = tid >> 2, scg = tid & 3;   // scan: 64 rows x 4 col-groups

    u32 v0 = 0, v1 = 0, v2 = 0, v3 = 0, v4 = 0, v5 = 0;

    for (int nt = 0; nt < 2; nt++) {
        f32x4 acc[2][4] = {};
        kloop64<512, 4>(Ah + (size_t)m0 * 512,
                        Bt + (size_t)(cb0 + nt * 128) * 512, Alds, Blds, acc);
        #pragma unroll
        for (int half = 0; half < 2; half++) {
            __syncthreads();
            if ((wave >> 1) == half) {
                #pragma unroll
                for (int mi = 0; mi < 2; mi++)
                    #pragma unroll
                    for (int ni = 0; ni < 4; ni++)
                        #pragma unroll
                        for (int i = 0; i < 4; i++) {
                            int colLocal = nt * 128 + half * 64 + ni * 16 + lr;
                            S[(wm + mi * 16 + quad * 4 + i) * 65 + ni * 16 + lr]
                                = pack_vi(acc[mi][ni][i], 255 - colLocal);
                        }
            }
            __syncthreads();
            const u32* Sr = &S[srow * 65 + scg * 16];
            #pragma unroll
            for (int c = 0; c < 16; c++) {
                u32 x = Sr[c];
                v5 = max(v5, min(v4, x));
                v4 = max(v4, min(v3, x));
                v3 = max(v3, min(v2, x));
                v2 = max(v2, min(v1, x));
                v1 = max(v1, min(v0, x));
                v0 = max(v0, x);
            }
        }
    }
    // merge the four column-group lists per row through LDS
    __syncthreads();
    {
        u32* dst = &S[srow * 65 + scg * 6];
        dst[0] = v0; dst[1] = v1; dst[2] = v2; dst[3] = v3; dst[4] = v4; dst[5] = v5;
    }
    __syncthreads();
    if (tid < 64) {
        u32 m0v = 0, m1v = 0, m2v = 0, m3v = 0, m4v = 0, m5v = 0;
        const u32* Sr = &S[tid * 65];
        #pragma unroll
        for (int s = 0; s < 24; s++) {
            u32 x = Sr[s];
            m5v = max(m5v, min(m4v, x));
            m4v = max(m4v, min(m3v, x));
            m3v = max(m3v, min(m2v, x));
            m2v = max(m2v, min(m1v, x));
            m1v = max(m1v, min(m0v, x));
            m0v = max(m0v, x);
        }
        u32* dst = tvp + (size_t)(m0 + tid) * 192 + blockIdx.x * 6;
        dst[0] = m0v; dst[1] = m1v; dst[2] = m2v;
        dst[3] = m3v; dst[4] = m4v; dst[5] = m5v;
    }
}

// merge 32 packed partial top-6 lists per row -> final top-6 (fp32 val + idx)
__global__ void topk_merge(const u32* __restrict__ tvp,
                           float* __restrict__ tv, int* __restrict__ ti)
{
    int r = blockIdx.x * 64 + threadIdx.x;
    u32 v[6]; int ix[6];
    #pragma unroll
    for (int j = 0; j < 6; j++) { v[j] = 0; ix[j] = 0; }
    const u32* pv = tvp + (size_t)r * 192;
    for (int b = 0; b < 32; b++) {
        #pragma unroll
        for (int j2 = 0; j2 < 6; j2++) {
            u32 p = pv[b * 6 + j2];
            if (p <= v[5]) break;     // group is descending: rest can't insert
            v[5] = p; ix[5] = b * 256 + 255 - (int)(p & 255u);
            #pragma unroll
            for (int j = 5; j > 0; j--) {
                if (v[j] > v[j - 1]) {
                    u32 tf = v[j]; v[j] = v[j - 1]; v[j - 1] = tf;
                    int tx = ix[j]; ix[j] = ix[j - 1]; ix[j - 1] = tx;
                }
            }
        }
    }
    #pragma unroll
    for (int j = 0; j < 6; j++) {
        tv[(size_t)r * 6 + j] = unpack_v(v[j]) * SCALE_F;
        ti[(size_t)r * 6 + j] = ix[j];
    }
}

// ---------------------------------------------------------------------------
// neighbor aggregation, one WAVE per row (no block barriers). fp32 math.
__global__ __launch_bounds__(256) void neighbor_kernel(
    const u16* __restrict__ eH, const u16* __restrict__ eT,
    const float* __restrict__ tv, const int* __restrict__ ti,
    u16* __restrict__ s1, u16* __restrict__ s2)
{
    const int tid = threadIdx.x, wave = tid >> 6, lane = tid & 63;
    const int n = blockIdx.x * 4 + wave;
    float tw[6]; int id[6];
    #pragma unroll
    for (int j = 0; j < 6; j++) {
        tw[j] = tv[n * 6 + j];
        int t = ti[n * 6 + j];
        id[j] = ((unsigned)t < 8192u) ? t : 0;
    }
    float mx = tw[0];
    #pragma unroll
    for (int j = 1; j < 6; j++) mx = fmaxf(mx, tw[j]);
    float p[6]; float ps = 0.f;
    #pragma unroll
    for (int j = 0; j < 6; j++) { p[j] = __expf(tw[j] - mx); ps += p[j]; }
    float inv = 1.0f / ps;
    #pragma unroll
    for (int j = 0; j < 6; j++) p[j] *= inv;

    const size_t base = (size_t)n * 512 + lane * 8;
    float eh[8];
    { bh8 v = *(const bh8*)(eH + base);
      #pragma unroll
      for (int c = 0; c < 8; c++) eh[c] = (float)v[c]; }
    float nb[6][8];
    #pragma unroll
    for (int j = 0; j < 6; j++) {
        bh8 v = *(const bh8*)(eT + (size_t)id[j] * 512 + lane * 8);
        #pragma unroll
        for (int c = 0; c < 8; c++) nb[j][c] = (float)v[c];
    }
    float ka[6];
    #pragma unroll
    for (int j = 0; j < 6; j++) {
        float s = 0.f;
        #pragma unroll
        for (int c = 0; c < 8; c++) {
            float e = p[j] * nb[j][c] + (1.f - p[j]) * eh[c];
            float x = eh[c] + e;
            x = fminf(fmaxf(x, -15.f), 15.f);
            float ex = __expf(2.f * x);
            float g = 1.f - 2.f / (ex + 1.f);   // tanh
            s += nb[j][c] * g;
        }
        #pragma unroll
        for (int off = 32; off > 0; off >>= 1) s += __shfl_down(s, off);
        ka[j] = __shfl(s, 0);
    }
    float m2 = ka[0];
    #pragma unroll
    for (int j = 1; j < 6; j++) m2 = fmaxf(m2, ka[j]);
    float kp[6]; float ks = 0.f;
    #pragma unroll
    for (int j = 0; j < 6; j++) { kp[j] = __expf(ka[j] - m2); ks += kp[j]; }
    float inv2 = 1.0f / ks;
    #pragma unroll
    for (int j = 0; j < 6; j++) kp[j] *= inv2;
    bh8 o1, o2;
    #pragma unroll
    for (int c = 0; c < 8; c++) {
        float eN = 0.f;
        #pragma unroll
        for (int j = 0; j < 6; j++) eN += kp[j] * nb[j][c];
        o1[c] = (bh)(eh[c] + eN);
        o2[c] = (bh)(eh[c] * eN);
    }
    *(bh8*)(s1 + base) = o1;
    *(bh8*)(s2 + base) = o2;
}

// ---------------------------------------------------------------------------
__global__ void colsum_kernel(const u16* __restrict__ h, float* __restrict__ colsum) {
    int tid = threadIdx.x;
    int n0 = blockIdx.x * 32;
    float a0 = 0.f, a1 = 0.f;
    for (int k = 0; k < 32; k++) {
        size_t b = (size_t)(n0 + k) * 512;
        a0 += bf2f(h[b + tid]); a1 += bf2f(h[b + tid + 256]);
    }
    atomicAdd(&colsum[tid], a0);
    atomicAdd(&colsum[tid + 256], a1);
}

__global__ void meanmix_kernel(u16* __restrict__ h, const float* __restrict__ colsum) {
    size_t i = ((size_t)blockIdx.x * 256 + threadIdx.x) * 8;
    int col = (int)(i & 511);
    union { int4 v; u16 s[8]; } u;
    u.v = *(const int4*)&h[i];
    #pragma unroll
    for (int j = 0; j < 8; j++)
        u.s[j] = f2bf((bf2f(u.s[j]) + colsum[col + j] * (1.0f / 8192.0f)) * 0.5f);
    *(int4*)&h[i] = u.v;
}

__global__ __launch_bounds__(256) void att2_kernel(
    const float* __restrict__ a1, const float* __restrict__ w,
    const float* __restrict__ b, float* __restrict__ att)
{
    int row = blockIdx.x * 4 + (threadIdx.x >> 6);
    int lane = threadIdx.x & 63;
    const float* pr = a1 + (size_t)row * 256;
    float s = 0.f;
    #pragma unroll
    for (int k = 0; k < 4; k++) { int c = lane + k * 64; s += pr[c] * w[c]; }
    #pragma unroll
    for (int off = 32; off > 0; off >>= 1) s += __shfl_down(s, off);
    if (lane == 0) att[row] = s + b[0];
}

// parallel softmax stats: ordered-u32 atomicMax, then atomicAdd of exp sums
__global__ void att_max(const float* __restrict__ att, u32* __restrict__ scal_u) {
    int i = blockIdx.x * 256 + threadIdx.x;
    int lane = threadIdx.x & 63;
    u32 o = ordf(att[i]);
    #pragma unroll
    for (int off = 32; off > 0; off >>= 1) o = max(o, (u32)__shfl_down((int)o, off));
    if (lane == 0) atomicMax(&scal_u[0], o);
}
__global__ void att_sum(const float* __restrict__ att, float* __restrict__ scal) {
    int i = blockIdx.x * 256 + threadIdx.x;
    int lane = threadIdx.x & 63;
    float mx = unordf(((const u32*)scal)[0]);
    float e = __expf(att[i] - mx);
    #pragma unroll
    for (int off = 32; off > 0; off >>= 1) e += __shfl_down(e, off);
    if (lane == 0) atomicAdd(&scal[1], e);
}

__global__ void pooled_kernel(const u16* __restrict__ emb, const float* __restrict__ att,
                              const float* __restrict__ scal, float* __restrict__ pooled) {
    int tid = threadIdx.x;
    int n0 = blockIdx.x * 32;
    float mx = unordf(((const u32*)scal)[0]);
    float inv = 1.0f / scal[1];
    float a0 = 0.f, a1 = 0.f;
    for (int k = 0; k < 32; k++) {
        int n = n0 + k;
        float w = __expf(att[n] - mx) * inv;
        size_t b = (size_t)n * 512;
        a0 += w * bf2f(emb[b + tid]);
        a1 += w * bf2f(emb[b + tid + 256]);
    }
    atomicAdd(&pooled[tid], a0);
    atomicAdd(&pooled[tid + 256], a1);
}

__global__ void final_kernel(const float* __restrict__ pooled,
                             const float* __restrict__ g, const float* __restrict__ bln,
                             const float* __restrict__ fcw, const float* __restrict__ fcb,
                             float* __restrict__ out) {
    __shared__ float red[256];
    int tid = threadIdx.x;
    float x0 = pooled[tid], x1 = pooled[tid + 256];
    red[tid] = x0 + x1; __syncthreads();
    for (int s = 128; s > 0; s >>= 1) { if (tid < s) red[tid] += red[tid + s]; __syncthreads(); }
    float mu = red[0] * (1.0f / 512.0f); __syncthreads();
    float d0 = x0 - mu, d1 = x1 - mu;
    red[tid] = d0 * d0 + d1 * d1; __syncthreads();
    for (int s = 128; s > 0; s >>= 1) { if (tid < s) red[tid] += red[tid + s]; __syncthreads(); }
    float var = red[0] * (1.0f / 512.0f); __syncthreads();
    float rstd = rsqrtf(var + 1e-5f);
    float l0 = d0 * rstd * g[tid]       + bln[tid];
    float l1 = d1 * rstd * g[tid + 256] + bln[tid + 256];
    red[tid] = l0 * fcw[tid * 2] + l1 * fcw[(tid + 256) * 2]; __syncthreads();
    for (int s = 128; s > 0; s >>= 1) { if (tid < s) red[tid] += red[tid + s]; __syncthreads(); }
    float o0 = red[0] + fcb[0]; __syncthreads();
    red[tid] = l0 * fcw[tid * 2 + 1] + l1 * fcw[(tid + 256) * 2 + 1]; __syncthreads();
    for (int s = 128; s > 0; s >>= 1) { if (tid < s) red[tid] += red[tid + s]; __syncthreads(); }
    float o1 = red[0] + fcb[1];
    if (tid == 0) {
        float m = fmaxf(o0, o1);
        float e0 = expf(o0 - m), e1 = expf(o1 - m);
        float se = e0 + e1;
        out[0] = o0;
        out[1] = o1;
        out[2] = e0 / se;
        out[3] = e1 / se;
        out[4] = (o0 >= o1) ? 0.0f : 1.0f;
    }
}

// ---------------------------------------------------------------------------
extern "C" void kernel_launch(void* const* d_in, const int* in_sizes, int n_in,
                              void* d_out, int out_size, void* d_ws, size_t ws_size,
                              hipStream_t stream)
{
    const float* x      = (const float*)d_in[0];
    const float* fc1_w  = (const float*)d_in[1];
    const float* fc1_b  = (const float*)d_in[2];
    const float* wh_w   = (const float*)d_in[3];
    const float* wh_b   = (const float*)d_in[4];
    const float* wt_w   = (const float*)d_in[5];
    const float* wt_b   = (const float*)d_in[6];
    const float* lin1_w = (const float*)d_in[7];
    const float* lin1_b = (const float*)d_in[8];
    const float* lin2_w = (const float*)d_in[9];
    const float* lin2_b = (const float*)d_in[10];
    const float* att1_w = (const float*)d_in[11];
    const float* att1_b = (const float*)d_in[12];
    const float* att2_w = (const float*)d_in[13];
    const float* att2_b = (const float*)d_in[14];
    const float* ln_g   = (const float*)d_in[15];
    const float* ln_b   = (const float*)d_in[16];
    const float* fc_w   = (const float*)d_in[17];
    const float* fc_b   = (const float*)d_in[18];
    float* out = (float*)d_out;
    char* ws = (char*)d_ws;

    u16*   fc1T   = (u16*)(ws + 0);
    u16*   whT    = (u16*)(ws + 1048576);
    u16*   wtT    = (u16*)(ws + 1572864);
    u16*   l1T    = (u16*)(ws + 2097152);
    u16*   l2T    = (u16*)(ws + 2621440);
    u16*   a1T    = (u16*)(ws + 3145728);
    float* tv     = (float*)(ws + 3407872);
    int*   ti     = (int*)(ws + 3604480);
    float* att    = (float*)(ws + 3801088);
    float* colsum = (float*)(ws + 3833856);
    float* pooled = (float*)(ws + 3835904);
    float* scal   = (float*)(ws + 3837952);
    u32*   tvp    = (u32*)(ws + 4194304);
    u16*   hbf    = (u16*)(ws + 14680064);   // 8 MB  [h; later s1]
    u16*   ehbf   = (u16*)(ws + 23068672);   // 8 MB  [e_h; later a1 fp32]
    u16*   etbf   = (u16*)(ws + 31457280);   // 8 MB  [e_t; later emb]
    u16*   s2bf   = (u16*)(ws + 39845888);   // 8 MB  [s2]
    u16*   xbf    = (u16*)(ws + 23068672);   // 16 MB (x bf16; dead after fc1)
    float* a1f    = (float*)(ws + 23068672); // 8 MB fp32 (after e_h dead)

    transpose_cvt<<<5760, dim3(32, 8), 0, stream>>>(
        fc1_w, fc1T, wh_w, whT, wt_w, wtT, lin1_w, l1T, lin2_w, l2T, att1_w, a1T, x, xbf);
    hipMemsetAsync(colsum, 0, 4160, stream);   // colsum + pooled + scal

    gemm64<1, 0, 1024><<<dim3(8, 128), 256, 0, stream>>>(xbf, fc1T, fc1_b, nullptr, hbf, 512);
    colsum_kernel<<<256, 256, 0, stream>>>(hbf, colsum);
    meanmix_kernel<<<2048, 256, 0, stream>>>(hbf, colsum);

    ehet64<<<dim3(16, 128), 256, 0, stream>>>(hbf, whT, wtT, wh_b, wt_b, ehbf, etbf);

    logits_topk<<<dim3(32, 128), 256, 0, stream>>>(ehbf, etbf, tvp);
    topk_merge<<<128, 64, 0, stream>>>(tvp, tv, ti);

    neighbor_kernel<<<2048, 256, 0, stream>>>(ehbf, etbf, tv, ti, hbf, s2bf);

    lin12_64<<<dim3(8, 128), 256, 0, stream>>>(hbf, l1T, lin1_b, s2bf, l2T, lin2_b, etbf);

    gemm64<2, 1, 512><<<dim3(4, 128), 256, 0, stream>>>(etbf, a1T, att1_b, a1f, nullptr, 256);
    att2_kernel<<<2048, 256, 0, stream>>>(a1f, att2_w, att2_b, att);
    att_max<<<32, 256, 0, stream>>>(att, (u32*)scal);
    att_sum<<<32, 256, 0, stream>>>(att, scal);
    pooled_kernel<<<256, 256, 0, stream>>>(etbf, att, scal, pooled);

    final_kernel<<<1, 256, 0, stream>>>(pooled, ln_g, ln_b, fc_w, fc_b, out);
}